// Round 2
// baseline (1450.282 us; speedup 1.0000x reference)
//
#include <hip/hip_runtime.h>
#include <hip/hip_bf16.h>
#include <math.h>

constexpr int Bc   = 4;
constexpr int Nc   = 200;
constexpr int Cc   = 64;
constexpr int Mc   = 600;    // 3*N
constexpr int ATTc = 128;
constexpr int OUTFc = 128;
constexpr int PREDc = 12;
constexpr int MAXBW = 40;
constexpr int MPAD  = 640;   // padded V^T leading dim
constexpr int PST   = 132;   // P scratch stride (shorts): 66 dwords -> 2-bank row shift

typedef short short4v __attribute__((ext_vector_type(4)));
typedef short short8 __attribute__((ext_vector_type(8)));
typedef float f32x4  __attribute__((ext_vector_type(4)));

static __device__ __forceinline__ void bsplit(float v, short& h, short& l) {
    __hip_bfloat16 hb = __float2bfloat16(v);
    float hf = __bfloat162float(hb);
    __hip_bfloat16 lb = __float2bfloat16(v - hf);
    h = *(short*)&hb; l = *(short*)&lb;
}

// ---------------- embed + sliding window ----------------
__global__ __launch_bounds__(256)
void embed_window_k(const float* __restrict__ src, const float* __restrict__ temb,
                    const float* __restrict__ semb, float* __restrict__ dst,
                    int Tin, int nw, long total)
{
    long idx = (long)blockIdx.x * 256 + threadIdx.x;
    if (idx >= total) return;
    int c = (int)(idx & 63);
    long r = idx >> 6;
    int n = (int)(r % Nc); r /= Nc;
    int j = (int)(r % 3);  r /= 3;
    int w = (int)(r % nw);
    int b = (int)(r / nw);
    int t = w + j;
    dst[idx] = src[(((long)b * Tin + t) * Nc + n) * Cc + c]
             + temb[t * Cc + c] + semb[n * Cc + c];
}

// ------- fused node-mean + NA/NB projection -> bf16 hi/lo outputs ---------
__global__ __launch_bounds__(256)
void mean_nab_k(const float* __restrict__ cur, const float* __restrict__ Wa,
                const float* __restrict__ Wb,
                ushort* __restrict__ NAH, ushort* __restrict__ NAL,
                ushort* __restrict__ NBH, ushort* __restrict__ NBL, int BW)
{
    __shared__ float Ns[64][17];   // [k][row]
    __shared__ float Ws[64][132];  // [k][ Wa | Wb ]
    const int m0 = blockIdx.x * 16;
    const int t = threadIdx.x;
    for (int e = t; e < 1024; e += 256) {
        int r = e >> 4, c4 = (e & 15) << 2;
        *(float4*)&Ws[r][c4]      = *(const float4*)&Wa[r * 64 + c4];
        *(float4*)&Ws[r][64 + c4] = *(const float4*)&Wb[r * 64 + c4];
    }
    {
        int row = t >> 4, c4 = (t & 15) << 2;
        int gm = m0 + row;
        float4 sv = make_float4(0.f, 0.f, 0.f, 0.f);
        if (gm < Mc) {
            for (int bw = 0; bw < BW; bw++) {
                const float4 v = *(const float4*)&cur[((long)bw * Mc + gm) * Cc + c4];
                sv.x += v.x; sv.y += v.y; sv.z += v.z; sv.w += v.w;
            }
        }
        const float inv = 1.f / BW;
        Ns[c4 + 0][row] = sv.x * inv; Ns[c4 + 1][row] = sv.y * inv;
        Ns[c4 + 2][row] = sv.z * inv; Ns[c4 + 3][row] = sv.w * inv;
    }
    __syncthreads();
    const int row = t >> 4, c8 = (t & 15) * 8;
    float acc[8] = {};
    for (int k = 0; k < 64; k++) {
        float a = Ns[k][row];
        float b[8];
        *(float4*)&b[0] = *(const float4*)&Ws[k][c8];
        *(float4*)&b[4] = *(const float4*)&Ws[k][c8 + 4];
#pragma unroll
        for (int j = 0; j < 8; j++) acc[j] += a * b[j];
    }
    int gm = m0 + row;
    if (gm < Mc) {
#pragma unroll
        for (int j = 0; j < 8; j++) {
            int col = c8 + j;
            short h, l;
            bsplit(acc[j], h, l);
            if (col < 64) { NAH[gm * 64 + col] = (ushort)h; NAL[gm * 64 + col] = (ushort)l; }
            else { NBH[gm * 64 + col - 64] = (ushort)h; NBL[gm * 64 + col - 64] = (ushort)l; }
        }
    }
}

// ---- adj = sigmoid( (NA NB^T) / 8 ): split-bf16 MFMA, 128-tiles, grid 5x5 -
__global__ __launch_bounds__(256)
void adjmm_k(const ushort* __restrict__ Ah, const ushort* __restrict__ Al,
             const ushort* __restrict__ Bh, const ushort* __restrict__ Bl,
             float* __restrict__ ADJ)
{
    __shared__ __align__(16) ushort As[2][128][40];
    __shared__ __align__(16) ushort Bs[2][128][40];
    const int m0 = blockIdx.y * 128, n0 = blockIdx.x * 128;
    const int t = threadIdx.x;
    const int lane = t & 63, w = t >> 6;
    const int wm = (w >> 1) * 64, wn = (w & 1) * 64;
    const int lm = lane & 15, lq = lane >> 4;

    f32x4 acc[4][4];
#pragma unroll
    for (int i = 0; i < 4; i++)
#pragma unroll
        for (int j = 0; j < 4; j++)
#pragma unroll
            for (int r = 0; r < 4; r++) acc[i][j][r] = 0.f;

    for (int k0 = 0; k0 < 64; k0 += 32) {
        __syncthreads();
#pragma unroll
        for (int p = 0; p < 2; p++) {
            int e = t + p * 256;
            int row = e >> 2, ks = (e & 3) << 3;
            {
                int gm = m0 + row;
                short8 vh, vl;
#pragma unroll
                for (int q = 0; q < 8; q++) { vh[q] = 0; vl[q] = 0; }
                if (gm < Mc) {
                    vh = *(const short8*)(Ah + (long)gm * 64 + k0 + ks);
                    vl = *(const short8*)(Al + (long)gm * 64 + k0 + ks);
                }
                *(short8*)&As[0][row][ks] = vh;
                *(short8*)&As[1][row][ks] = vl;
            }
            {
                int gn = n0 + row;
                short8 vh, vl;
#pragma unroll
                for (int q = 0; q < 8; q++) { vh[q] = 0; vl[q] = 0; }
                if (gn < Mc) {
                    vh = *(const short8*)(Bh + (long)gn * 64 + k0 + ks);
                    vl = *(const short8*)(Bl + (long)gn * 64 + k0 + ks);
                }
                *(short8*)&Bs[0][row][ks] = vh;
                *(short8*)&Bs[1][row][ks] = vl;
            }
        }
        __syncthreads();

        short8 af[4][2], bf[4][2];
#pragma unroll
        for (int i = 0; i < 4; i++) {
            af[i][0] = *(const short8*)&As[0][wm + i * 16 + lm][lq * 8];
            af[i][1] = *(const short8*)&As[1][wm + i * 16 + lm][lq * 8];
        }
#pragma unroll
        for (int j = 0; j < 4; j++) {
            bf[j][0] = *(const short8*)&Bs[0][wn + j * 16 + lm][lq * 8];
            bf[j][1] = *(const short8*)&Bs[1][wn + j * 16 + lm][lq * 8];
        }
#pragma unroll
        for (int i = 0; i < 4; i++)
#pragma unroll
            for (int j = 0; j < 4; j++) {
                acc[i][j] = __builtin_amdgcn_mfma_f32_16x16x32_bf16(af[i][0], bf[j][0], acc[i][j], 0, 0, 0);
                acc[i][j] = __builtin_amdgcn_mfma_f32_16x16x32_bf16(af[i][0], bf[j][1], acc[i][j], 0, 0, 0);
                acc[i][j] = __builtin_amdgcn_mfma_f32_16x16x32_bf16(af[i][1], bf[j][0], acc[i][j], 0, 0, 0);
            }
    }
#pragma unroll
    for (int i = 0; i < 4; i++) {
        int gmb = m0 + wm + i * 16 + lq * 4;
#pragma unroll
        for (int j = 0; j < 4; j++) {
            int gn = n0 + wn + j * 16 + lm;
            if (gn >= Mc) continue;
#pragma unroll
            for (int r = 0; r < 4; r++) {
                int gm = gmb + r;
                if (gm < Mc)
                    ADJ[(long)gm * Mc + gn] = 1.f / (1.f + __expf(-acc[i][j][r] * 0.125f));
            }
        }
    }
}

// ---------------- Wqkv^T prep: transpose + bf16 hi/lo split ----------------
// WQH/WQL [384][64]: row = output column of Wqkv, col = input channel.
__global__ __launch_bounds__(256)
void wqkv_prep_k(const float* __restrict__ Wqkv,
                 ushort* __restrict__ WQH, ushort* __restrict__ WQL)
{
    int i = blockIdx.x * 256 + threadIdx.x;
    if (i >= 384 * 64) return;
    int n = i >> 6, c = i & 63;
    short h, l;
    bsplit(Wqkv[c * 384 + n], h, l);
    WQH[n * 64 + c] = (ushort)h;
    WQL[n * 64 + c] = (ushort)l;
}

// ---- QKV projection: split-bf16 MFMA, K=64, XCD-swizzled ------------------
// A = CUR tile (fp32 -> hi/lo in staging), B = WqkvT hi/lo. C routed through
// packed-uint LDS scratch so all global stores are short8 (no amplification).
__global__ __launch_bounds__(256)
void qkv_mfma_k(const float* __restrict__ CURp,
                const ushort* __restrict__ WQH, const ushort* __restrict__ WQL,
                const float* __restrict__ bias,
                ushort* __restrict__ QH, ushort* __restrict__ QL,
                ushort* __restrict__ KH, ushort* __restrict__ KL,
                ushort* __restrict__ VTH, ushort* __restrict__ VTL)
{
    __shared__ __align__(16) ushort SM[36864];   // 72 KB, multi-purpose
    ushort* AsH = SM;                 // [128][72]
    ushort* AsL = SM + 9216;
    ushort* BsH = SM + 18432;
    ushort* BsL = SM + 27648;
    const int bid = blockIdx.x;
    const int xcd = bid & 7, slot = bid >> 3;
    const int z = (slot / 15) * 8 + xcd;
    const int r15 = slot % 15;
    const int which = r15 % 3;             // 0=q 1=k 2=v
    const int m0 = (r15 / 3) * 128;
    const int nb = which * 128;
    const float* A = CURp + (long)z * Mc * Cc;
    const int t = threadIdx.x;
    const int lane = t & 63, w = t >> 6;
    const int wm = (w >> 1) * 64, wn = (w & 1) * 64;
    const int lm = lane & 15, lq = lane >> 4;

    // ---- stage A: CUR tile 128 rows x 64 k, fp32 -> hi/lo ----
#pragma unroll
    for (int p = 0; p < 8; p++) {
        int e = t + p * 256;              // 0..2047
        int row = e >> 4, k4 = (e & 15) * 4;
        int gm = m0 + row;
        float4 v = make_float4(0.f, 0.f, 0.f, 0.f);
        if (gm < Mc) v = *(const float4*)(A + (long)gm * 64 + k4);
        short4v h4, l4;
        short hs, ls;
        bsplit(v.x, hs, ls); h4[0] = hs; l4[0] = ls;
        bsplit(v.y, hs, ls); h4[1] = hs; l4[1] = ls;
        bsplit(v.z, hs, ls); h4[2] = hs; l4[2] = ls;
        bsplit(v.w, hs, ls); h4[3] = hs; l4[3] = ls;
        *(short4v*)(AsH + row * 72 + k4) = h4;
        *(short4v*)(AsL + row * 72 + k4) = l4;
    }
    // ---- stage B: WqkvT rows nb..nb+127 x 64 ----
#pragma unroll
    for (int p = 0; p < 4; p++) {
        int e = t + p * 256;              // 0..1023
        int row = e >> 3, seg = (e & 7) * 8;
        *(short8*)(BsH + row * 72 + seg) = *(const short8*)(WQH + (long)(nb + row) * 64 + seg);
        *(short8*)(BsL + row * 72 + seg) = *(const short8*)(WQL + (long)(nb + row) * 64 + seg);
    }
    __syncthreads();

    f32x4 acc[4][4];
#pragma unroll
    for (int i = 0; i < 4; i++)
#pragma unroll
        for (int j = 0; j < 4; j++)
#pragma unroll
            for (int r = 0; r < 4; r++) acc[i][j][r] = 0.f;

#pragma unroll
    for (int ks = 0; ks < 2; ks++) {
        short8 af[4][2], bf[4][2];
#pragma unroll
        for (int i = 0; i < 4; i++) {
            af[i][0] = *(const short8*)(AsH + (wm + i * 16 + lm) * 72 + ks * 32 + lq * 8);
            af[i][1] = *(const short8*)(AsL + (wm + i * 16 + lm) * 72 + ks * 32 + lq * 8);
        }
#pragma unroll
        for (int j = 0; j < 4; j++) {
            bf[j][0] = *(const short8*)(BsH + (wn + j * 16 + lm) * 72 + ks * 32 + lq * 8);
            bf[j][1] = *(const short8*)(BsL + (wn + j * 16 + lm) * 72 + ks * 32 + lq * 8);
        }
#pragma unroll
        for (int i = 0; i < 4; i++)
#pragma unroll
            for (int j = 0; j < 4; j++) {
                acc[i][j] = __builtin_amdgcn_mfma_f32_16x16x32_bf16(af[i][0], bf[j][0], acc[i][j], 0, 0, 0);
                acc[i][j] = __builtin_amdgcn_mfma_f32_16x16x32_bf16(af[i][0], bf[j][1], acc[i][j], 0, 0, 0);
                acc[i][j] = __builtin_amdgcn_mfma_f32_16x16x32_bf16(af[i][1], bf[j][0], acc[i][j], 0, 0, 0);
            }
    }
    __syncthreads();   // frags consumed; SM reused as C scratch

    // ---- C -> packed (hi|lo) uint LDS scratch, stride 132 ----
    uint* CP = (uint*)SM;                 // [128][132] uints = 67.6 KB
#pragma unroll
    for (int i = 0; i < 4; i++)
#pragma unroll
        for (int j = 0; j < 4; j++) {
            int col = wn + j * 16 + lm;
            float b = bias[nb + col];
#pragma unroll
            for (int r = 0; r < 4; r++) {
                int row = wm + i * 16 + lq * 4 + r;
                float v = acc[i][j][r] + b;
                if (which == 2) v = fmaxf(v, 0.f);
                short hs, ls;
                bsplit(v, hs, ls);
                CP[row * 132 + col] = ((uint)(ushort)ls << 16) | (uint)(ushort)hs;
            }
        }
    __syncthreads();

    if (which == 2) {
        // V: transposed packed store [col][MPAD] + row
        ushort* vh = VTH + (long)z * ATTc * MPAD;
        ushort* vl = VTL + (long)z * ATTc * MPAD;
#pragma unroll
        for (int p = 0; p < 8; p++) {
            int e = t + p * 256;          // 0..2047
            int col = e >> 4, rg = (e & 15) * 8;
            if (m0 + rg < Mc) {           // 600 % 8 == 0: whole group valid
                short8 h8, l8;
#pragma unroll
                for (int q = 0; q < 8; q++) {
                    uint u = CP[(rg + q) * 132 + col];
                    h8[q] = (short)(u & 0xffff);
                    l8[q] = (short)(u >> 16);
                }
                *(short8*)(vh + (long)col * MPAD + m0 + rg) = h8;
                *(short8*)(vl + (long)col * MPAD + m0 + rg) = l8;
            }
        }
    } else {
        // Q/K: row-major packed store [row][128]
        ushort* dh = (which == 0 ? QH : KH) + (long)z * Mc * ATTc;
        ushort* dl = (which == 0 ? QL : KL) + (long)z * Mc * ATTc;
#pragma unroll
        for (int p = 0; p < 8; p++) {
            int e = t + p * 256;
            int row = e >> 4, seg = (e & 15) * 8;
            int gm = m0 + row;
            if (gm < Mc) {
                short8 h8, l8;
#pragma unroll
                for (int q = 0; q < 8; q++) {
                    uint u = CP[row * 132 + seg + q];
                    h8[q] = (short)(u & 0xffff);
                    l8[q] = (short)(u >> 16);
                }
                *(short8*)(dh + (long)gm * ATTc + seg) = h8;
                *(short8*)(dl + (long)gm * ATTc + seg) = l8;
            }
        }
    }
}

// ---- fused attention: S=QK^T -> P=exp(s)*adj -> PV ------------------------
// R15: barrier-free direct-global K/V. All 10 blocks of a z sit on one XCD,
// so K+V (614 KB/z, ~3 MB/XCD) is L2-resident; per-wave fragment loads are
// fully-coalesced 64B segments. LDS holds only the wave-private P scratch
// (stride 132 shorts = 66 dwords -> b16 writes are 2-way/free). No
// __syncthreads anywhere -> waves of the 3 co-resident blocks run async.
__global__ __launch_bounds__(256, 3)
void attn_k(const ushort* __restrict__ QH, const ushort* __restrict__ QL,
            const ushort* __restrict__ KH, const ushort* __restrict__ KL,
            const ushort* __restrict__ VTH, const ushort* __restrict__ VTL,
            const float* __restrict__ adj, uint* __restrict__ OB, float scale)
{
    __shared__ __align__(16) ushort PH[4][16][PST];   // wave-private P hi
    __shared__ __align__(16) ushort PL[4][16][PST];   //                lo
    const int bid = blockIdx.x;
    const int xcd = bid & 7, slot = bid >> 3;
    const int z = (slot / 10) * 8 + xcd;
    const int m0 = (slot % 10) * 64;
    const int t = threadIdx.x;
    const int lane = t & 63, w = t >> 6;
    const int lm = lane & 15, lq = lane >> 4;
    const int qrow0 = m0 + w * 16;

    const ushort* Qhz = QH + (long)z * Mc * ATTc;
    const ushort* Qlz = QL + (long)z * Mc * ATTc;
    const ushort* Khz = KH + (long)z * Mc * ATTc;
    const ushort* Klz = KL + (long)z * Mc * ATTc;
    const ushort* Vhz = VTH + (long)z * ATTc * MPAD;
    const ushort* Vlz = VTL + (long)z * ATTc * MPAD;

    // ---- Q fragments ----
    short8 qh[4], ql[4];
    {
        int qr = qrow0 + lm;
        if (qr < Mc) {
            const ushort* qp = Qhz + (long)qr * ATTc;
            const ushort* qp2 = Qlz + (long)qr * ATTc;
#pragma unroll
            for (int ks = 0; ks < 4; ks++) {
                qh[ks] = *(const short8*)(qp + ks * 32 + lq * 8);
                ql[ks] = *(const short8*)(qp2 + ks * 32 + lq * 8);
            }
        } else {
#pragma unroll
            for (int ks = 0; ks < 4; ks++)
#pragma unroll
                for (int q = 0; q < 8; q++) { qh[ks][q] = 0; ql[ks][q] = 0; }
        }
    }

    f32x4 oacc[8];
#pragma unroll
    for (int j = 0; j < 8; j++)
#pragma unroll
        for (int r = 0; r < 4; r++) oacc[j][r] = 0.f;
    float Er[4] = {}, Sr[4] = {};

    for (int c = 0; c < 5; c++) {       // 5 key chunks of 128
        const int kc = c * 128;
        f32x4 sacc[8];
#pragma unroll
        for (int j = 0; j < 8; j++)
#pragma unroll
            for (int r = 0; r < 4; r++) sacc[j][r] = 0.f;

        // ---- QK phase: 4 att-slices, K fragments direct from global ----
#pragma unroll
        for (int s = 0; s < 4; s++) {
            const int ao = s * 32 + lq * 8;
#pragma unroll
            for (int h = 0; h < 2; h++) {
                short8 bh[4], bl[4];
#pragma unroll
                for (int u = 0; u < 4; u++) {
                    int key = kc + (h * 4 + u) * 16 + lm;
                    key = key < Mc ? key : Mc - 1;       // clamp: OOB cols discarded later
                    bh[u] = *(const short8*)(Khz + (long)key * ATTc + ao);
                    bl[u] = *(const short8*)(Klz + (long)key * ATTc + ao);
                }
#pragma unroll
                for (int u = 0; u < 4; u++) {
                    int j = h * 4 + u;
                    sacc[j] = __builtin_amdgcn_mfma_f32_16x16x32_bf16(qh[s], bh[u], sacc[j], 0, 0, 0);
                    sacc[j] = __builtin_amdgcn_mfma_f32_16x16x32_bf16(qh[s], bl[u], sacc[j], 0, 0, 0);
                    sacc[j] = __builtin_amdgcn_mfma_f32_16x16x32_bf16(ql[s], bh[u], sacc[j], 0, 0, 0);
                }
            }
        }

        // ---- epilogue: adj loads overlap the exp chain ----
        float adjv[8][4];
#pragma unroll
        for (int j = 0; j < 8; j++) {
            int col = kc + j * 16 + lm;
#pragma unroll
            for (int r = 0; r < 4; r++) {
                int row = qrow0 + lq * 4 + r;
                adjv[j][r] = (col < Mc && row < Mc) ? adj[(long)row * Mc + col] : 0.f;
            }
        }
#pragma unroll
        for (int j = 0; j < 8; j++) {
            int col = kc + j * 16 + lm;
            bool cok = col < Mc;
            int cs = (j * 16 + lm) ^ (lq << 3);
#pragma unroll
            for (int r = 0; r < 4; r++) {
                float e = cok ? __expf(sacc[j][r] * scale) : 0.f;
                float p = e * adjv[j][r];
                Er[r] += e; Sr[r] += p;
                short hs, ls;
                bsplit(p, hs, ls);
                PH[w][lq * 4 + r][cs] = (ushort)hs;
                PL[w][lq * 4 + r][cs] = (ushort)ls;
            }
        }

        // ---- PV phase: 4 key-slices, V fragments direct from global ----
#pragma unroll
        for (int s = 0; s < 4; s++) {
            const int ko = kc + s * 32 + lq * 8;          // < MPAD, in buffer
            const int po = (s * 32 + lq * 8) ^ ((lm >> 2) << 3);
            short8 ph = *(const short8*)&PH[w][lm][po];
            short8 pl = *(const short8*)&PL[w][lm][po];
#pragma unroll
            for (int h = 0; h < 2; h++) {
                short8 vh[4], vl[4];
#pragma unroll
                for (int u = 0; u < 4; u++) {
                    int att = (h * 4 + u) * 16 + lm;
                    vh[u] = *(const short8*)(Vhz + (long)att * MPAD + ko);
                    vl[u] = *(const short8*)(Vlz + (long)att * MPAD + ko);
                }
#pragma unroll
                for (int u = 0; u < 4; u++) {
                    int j = h * 4 + u;
                    oacc[j] = __builtin_amdgcn_mfma_f32_16x16x32_bf16(ph, vh[u], oacc[j], 0, 0, 0);
                    oacc[j] = __builtin_amdgcn_mfma_f32_16x16x32_bf16(ph, vl[u], oacc[j], 0, 0, 0);
                    oacc[j] = __builtin_amdgcn_mfma_f32_16x16x32_bf16(pl, vh[u], oacc[j], 0, 0, 0);
                }
            }
        }
    }

    // ---- row sums, then packed bf16 hi/lo store ----
#pragma unroll
    for (int mk = 1; mk <= 8; mk <<= 1)
#pragma unroll
        for (int r = 0; r < 4; r++) {
            Er[r] += __shfl_xor(Er[r], mk, 64);
            Sr[r] += __shfl_xor(Sr[r], mk, 64);
        }
    float inv[4];
#pragma unroll
    for (int r = 0; r < 4; r++) inv[r] = 1.f / (Sr[r] + 1e-8f * Er[r]);
    uint* Oz = OB + (long)z * Mc * ATTc;
#pragma unroll
    for (int j = 0; j < 8; j++)
#pragma unroll
        for (int r = 0; r < 4; r++) {
            int row = qrow0 + lq * 4 + r;
            if (row < Mc) {
                float v = oacc[j][r] * inv[r];
                short hs, ls;
                bsplit(v, hs, ls);
                Oz[(long)row * ATTc + j * 16 + lm] =
                    ((uint)(ushort)ls << 16) | (uint)(ushort)hs;
            }
        }
}

// ---------------- Wlin^T prep: transpose + bf16 hi/lo split ----------------
__global__ __launch_bounds__(256)
void wlin_prep_k(const float* __restrict__ Wlin,
                 ushort* __restrict__ WTH, ushort* __restrict__ WTL)
{
    int i = blockIdx.x * 256 + threadIdx.x;
    if (i >= 64 * 128) return;
    int c = i >> 7, a = i & 127;
    short h, l;
    bsplit(Wlin[a * 64 + c], h, l);
    WTH[c * 128 + a] = (ushort)h;
    WTL[c * 128 + a] = (ushort)l;
}

// ---- Wlin GEMM: CUR = unpack(OB) @ Wlin + blin (split-bf16 MFMA) ----------
__global__ __launch_bounds__(256)
void wlin_k(const uint* __restrict__ OB, const ushort* __restrict__ WTH,
            const ushort* __restrict__ WTL, const float* __restrict__ blin,
            float* __restrict__ CUR, int Mtot)
{
    __shared__ __align__(16) ushort As[2][128][40];
    __shared__ __align__(16) ushort Bs[2][64][136];
    const int m0 = blockIdx.x * 128;
    const int t = threadIdx.x;
    const int lane = t & 63, w = t >> 6;
    const int wm = (w >> 1) * 64, wn = (w & 1) * 32;
    const int lm = lane & 15, lq = lane >> 4;

#pragma unroll
    for (int p = 0; p < 4; p++) {
        int e = t + p * 256;
        int row = e >> 4, seg = (e & 15) << 3;
        *(short8*)&Bs[0][row][seg] = *(const short8*)(WTH + row * 128 + seg);
        *(short8*)&Bs[1][row][seg] = *(const short8*)(WTL + row * 128 + seg);
    }

    f32x4 acc[4][2];
#pragma unroll
    for (int i = 0; i < 4; i++)
#pragma unroll
        for (int j = 0; j < 2; j++)
#pragma unroll
            for (int r = 0; r < 4; r++) acc[i][j][r] = 0.f;

    for (int k0 = 0; k0 < 128; k0 += 32) {
        __syncthreads();
#pragma unroll
        for (int p = 0; p < 2; p++) {
            int e = t + p * 256;
            int row = e >> 2, seg = (e & 3) << 3;
            int gm = m0 + row;
            short8 vh, vl;
#pragma unroll
            for (int q = 0; q < 8; q++) { vh[q] = 0; vl[q] = 0; }
            if (gm < Mtot) {
                const uint4 u0 = *(const uint4*)(OB + (long)gm * 128 + k0 + seg);
                const uint4 u1 = *(const uint4*)(OB + (long)gm * 128 + k0 + seg + 4);
#pragma unroll
                for (int q = 0; q < 4; q++) {
                    uint u = ((const uint*)&u0)[q];
                    vh[q] = (short)(u & 0xffff); vl[q] = (short)(u >> 16);
                }
#pragma unroll
                for (int q = 0; q < 4; q++) {
                    uint u = ((const uint*)&u1)[q];
                    vh[4 + q] = (short)(u & 0xffff); vl[4 + q] = (short)(u >> 16);
                }
            }
            *(short8*)&As[0][row][seg] = vh;
            *(short8*)&As[1][row][seg] = vl;
        }
        __syncthreads();

        short8 af[4][2], bf[2][2];
#pragma unroll
        for (int i = 0; i < 4; i++) {
            af[i][0] = *(const short8*)&As[0][wm + i * 16 + lm][lq * 8];
            af[i][1] = *(const short8*)&As[1][wm + i * 16 + lm][lq * 8];
        }
#pragma unroll
        for (int j = 0; j < 2; j++) {
            bf[j][0] = *(const short8*)&Bs[0][wn + j * 16 + lm][k0 + lq * 8];
            bf[j][1] = *(const short8*)&Bs[1][wn + j * 16 + lm][k0 + lq * 8];
        }
#pragma unroll
        for (int i = 0; i < 4; i++)
#pragma unroll
            for (int j = 0; j < 2; j++) {
                acc[i][j] = __builtin_amdgcn_mfma_f32_16x16x32_bf16(af[i][0], bf[j][0], acc[i][j], 0, 0, 0);
                acc[i][j] = __builtin_amdgcn_mfma_f32_16x16x32_bf16(af[i][0], bf[j][1], acc[i][j], 0, 0, 0);
                acc[i][j] = __builtin_amdgcn_mfma_f32_16x16x32_bf16(af[i][1], bf[j][0], acc[i][j], 0, 0, 0);
            }
    }
#pragma unroll
    for (int i = 0; i < 4; i++) {
        int gmb = m0 + wm + i * 16 + lq * 4;
#pragma unroll
        for (int j = 0; j < 2; j++) {
            int col = wn + j * 16 + lm;
            float b = blin[col];
#pragma unroll
            for (int r = 0; r < 4; r++) {
                int gm = gmb + r;
                if (gm < Mtot) CUR[(long)gm * 64 + col] = acc[i][j][r] + b;
            }
        }
    }
}

// ---------------- running max of middle-window slice [2N:3N] ---------------
__global__ __launch_bounds__(256)
void cand_update_k(const float* __restrict__ cur, float* __restrict__ cand,
                   int bw0, long total, int first)
{
    long idx = (long)blockIdx.x * 256 + threadIdx.x;
    if (idx >= total) return;
    int c = (int)(idx & 63);
    long r = idx >> 6;
    int n = (int)(r % Nc);
    int i = (int)(r / Nc);
    long bw = bw0 + i;
    float v = cur[((bw * Mc) + 2 * Nc + n) * Cc + c];
    long o = ((bw * Nc) + n) * Cc + c;
    cand[o] = first ? v : fmaxf(cand[o], v);
}

// ---------------- output layer ----------------
__global__ __launch_bounds__(128)
void output_k(const float* __restrict__ h2, const float* __restrict__ Wo,
              const float* __restrict__ bo, float* __restrict__ out)
{
    __shared__ float ds[512];
    int row = blockIdx.x;
    int b = row / Nc, n = row % Nc;
    int t = threadIdx.x;
    for (int e = t; e < 512; e += 128) {
        int tt = e >> 6, c = e & 63;
        ds[e] = h2[(((long)b * 8 + tt) * Nc + n) * Cc + c];
    }
    __syncthreads();
    float acc = bo[t];
    for (int e = 0; e < 512; e++) acc += ds[e] * Wo[e * OUTFc + t];
    acc = fmaxf(acc, 0.f);
    for (int p = 0; p < PREDc; p++)
        out[(((long)b * PREDc + p) * Nc + n) * (long)OUTFc + t] = acc;
}

extern "C" void kernel_launch(void* const* d_in, const int* in_sizes, int n_in,
                              void* d_out, int out_size, void* d_ws, size_t ws_size,
                              hipStream_t stream)
{
    (void)in_sizes; (void)n_in; (void)out_size; (void)ws_size;
    const float* x     = (const float*)d_in[0];
    const float* Wqkv  = (const float*)d_in[4];
    const float* bqkv  = (const float*)d_in[5];
    const float* Wlin  = (const float*)d_in[6];
    const float* blin  = (const float*)d_in[7];
    const float* Wa    = (const float*)d_in[8];
    const float* Wb    = (const float*)d_in[9];
    const float* temb0 = (const float*)d_in[13];
    const float* temb1 = (const float*)d_in[14];
    const float* semb  = (const float*)d_in[15];
    const float* Wo    = (const float*)d_in[16];
    const float* bo    = (const float*)d_in[17];
    float* out = (float*)d_out;

    // ---- workspace (float offsets), ~60 MB ----
    float* ws   = (float*)d_ws;
    float* CUR  = ws;                                  // 1,536,000
    float* ADJ  = CUR + (long)MAXBW * Mc * Cc;         // 360,000
    float* CAND = ADJ + (long)Mc * Mc;                 // 512,000
    uint*  OB   = (uint*)(CAND + (long)MAXBW * Nc * Cc); // 3,072,000 u32
    float* QHf  = (float*)(OB + (long)MAXBW * Mc * ATTc);
    const long QSZ = (long)MAXBW * Mc * ATTc / 2;      // in floats
    float* QLf  = QHf + QSZ;
    float* KHf  = QLf + QSZ;
    float* KLf  = KHf + QSZ;
    float* VTHf = KLf + QSZ;
    float* VTLf = VTHf + (long)MAXBW * ATTc * MPAD / 2;
    ushort* NAH = (ushort*)(VTLf + (long)MAXBW * ATTc * MPAD / 2);
    ushort* NAL = NAH + Mc * Cc;
    ushort* NBH = NAL + Mc * Cc;
    ushort* NBL = NBH + Mc * Cc;
    ushort* WTH = NBL + Mc * Cc;                       // 64*128 each
    ushort* WTL = WTH + 64 * 128;
    ushort* WQH = WTL + 64 * 128;                      // 384*64 each
    ushort* WQL = WQH + 384 * 64;

    ushort* QH  = (ushort*)QHf;
    ushort* QL  = (ushort*)QLf;
    ushort* KH  = (ushort*)KHf;
    ushort* KL  = (ushort*)KLf;
    ushort* VTH = (ushort*)VTHf;
    ushort* VTL = (ushort*)VTLf;

    const float inv_sqrt_att = 0.08838834764831845f;   // 1/sqrt(128)

    // weight preps (constant across iterations)
    wlin_prep_k<<<dim3(32), dim3(256), 0, stream>>>(Wlin, WTH, WTL);
    wqkv_prep_k<<<dim3(96), dim3(256), 0, stream>>>(Wqkv, WQH, WQL);

    for (int layer = 0; layer < 2; layer++) {
        int Tin = layer ? 10 : 12;
        int nw  = Tin - 2;
        int BW  = Bc * nw;                             // 40 then 32
        int Mtot = BW * Mc;
        const float* src  = layer ? CAND : x;
        const float* temb = layer ? temb1 : temb0;

        long etotal = (long)BW * Mc * Cc;
        embed_window_k<<<dim3((unsigned)((etotal + 255) / 256)), dim3(256), 0, stream>>>(
            src, temb, semb, CUR, Tin, nw, etotal);

        for (int it = 0; it < 3; it++) {
            // adjacency: mean -> NA/NB (bf16 split) -> sigmoid MFMA
            mean_nab_k<<<dim3(38), dim3(256), 0, stream>>>(
                CUR, Wa, Wb, NAH, NAL, NBH, NBL, BW);
            adjmm_k<<<dim3(5, 5), dim3(256), 0, stream>>>(
                NAH, NAL, NBH, NBL, ADJ);

            // QKV projection (split-bf16 MFMA, XCD-swizzled)
            qkv_mfma_k<<<dim3(BW * 15), dim3(256), 0, stream>>>(
                CUR, WQH, WQL, bqkv, QH, QL, KH, KL, VTH, VTL);

            // fused attention (R15: barrier-free, direct-global K/V)
            attn_k<<<dim3(BW * 10), dim3(256), 0, stream>>>(
                QH, QL, KH, KL, VTH, VTL, ADJ, OB, inv_sqrt_att);

            // cur = O @ Wlin + blin (split-bf16 MFMA)
            wlin_k<<<dim3((Mtot + 127) / 128), dim3(256), 0, stream>>>(
                OB, WTH, WTL, blin, CUR, Mtot);

            // running max of middle window
            long mtot = (long)BW * Nc * Cc;
            cand_update_k<<<dim3((unsigned)((mtot + 255) / 256)), dim3(256), 0, stream>>>(
                CUR, CAND, 0, mtot, it == 0 ? 1 : 0);
        }
    }
    output_k<<<dim3(Bc * Nc), dim3(128), 0, stream>>>(CAND, Wo, bo, out);
}

// Round 3
// 1022.621 us; speedup vs baseline: 1.4182x; 1.4182x over previous
//
#include <hip/hip_runtime.h>
#include <hip/hip_bf16.h>
#include <math.h>

constexpr int Bc   = 4;
constexpr int Nc   = 200;
constexpr int Cc   = 64;
constexpr int Mc   = 600;    // 3*N
constexpr int ATTc = 128;
constexpr int OUTFc = 128;
constexpr int PREDc = 12;
constexpr int MAXBW = 40;
constexpr int MPAD  = 640;   // padded V^T leading dim

typedef short short4v __attribute__((ext_vector_type(4)));
typedef short short8 __attribute__((ext_vector_type(8)));
typedef float f32x4  __attribute__((ext_vector_type(4)));
typedef float f32x16 __attribute__((ext_vector_type(16)));

static __device__ __forceinline__ void bsplit(float v, short& h, short& l) {
    __hip_bfloat16 hb = __float2bfloat16(v);
    float hf = __bfloat162float(hb);
    __hip_bfloat16 lb = __float2bfloat16(v - hf);
    h = *(short*)&hb; l = *(short*)&lb;
}

// ---------------- embed + sliding window ----------------
__global__ __launch_bounds__(256)
void embed_window_k(const float* __restrict__ src, const float* __restrict__ temb,
                    const float* __restrict__ semb, float* __restrict__ dst,
                    int Tin, int nw, long total)
{
    long idx = (long)blockIdx.x * 256 + threadIdx.x;
    if (idx >= total) return;
    int c = (int)(idx & 63);
    long r = idx >> 6;
    int n = (int)(r % Nc); r /= Nc;
    int j = (int)(r % 3);  r /= 3;
    int w = (int)(r % nw);
    int b = (int)(r / nw);
    int t = w + j;
    dst[idx] = src[(((long)b * Tin + t) * Nc + n) * Cc + c]
             + temb[t * Cc + c] + semb[n * Cc + c];
}

// ------- fused node-mean + NA/NB projection -> bf16 hi/lo outputs ---------
__global__ __launch_bounds__(256)
void mean_nab_k(const float* __restrict__ cur, const float* __restrict__ Wa,
                const float* __restrict__ Wb,
                ushort* __restrict__ NAH, ushort* __restrict__ NAL,
                ushort* __restrict__ NBH, ushort* __restrict__ NBL, int BW)
{
    __shared__ float Ns[64][17];   // [k][row]
    __shared__ float Ws[64][132];  // [k][ Wa | Wb ]
    const int m0 = blockIdx.x * 16;
    const int t = threadIdx.x;
    for (int e = t; e < 1024; e += 256) {
        int r = e >> 4, c4 = (e & 15) << 2;
        *(float4*)&Ws[r][c4]      = *(const float4*)&Wa[r * 64 + c4];
        *(float4*)&Ws[r][64 + c4] = *(const float4*)&Wb[r * 64 + c4];
    }
    {
        int row = t >> 4, c4 = (t & 15) << 2;
        int gm = m0 + row;
        float4 sv = make_float4(0.f, 0.f, 0.f, 0.f);
        if (gm < Mc) {
            for (int bw = 0; bw < BW; bw++) {
                const float4 v = *(const float4*)&cur[((long)bw * Mc + gm) * Cc + c4];
                sv.x += v.x; sv.y += v.y; sv.z += v.z; sv.w += v.w;
            }
        }
        const float inv = 1.f / BW;
        Ns[c4 + 0][row] = sv.x * inv; Ns[c4 + 1][row] = sv.y * inv;
        Ns[c4 + 2][row] = sv.z * inv; Ns[c4 + 3][row] = sv.w * inv;
    }
    __syncthreads();
    const int row = t >> 4, c8 = (t & 15) * 8;
    float acc[8] = {};
    for (int k = 0; k < 64; k++) {
        float a = Ns[k][row];
        float b[8];
        *(float4*)&b[0] = *(const float4*)&Ws[k][c8];
        *(float4*)&b[4] = *(const float4*)&Ws[k][c8 + 4];
#pragma unroll
        for (int j = 0; j < 8; j++) acc[j] += a * b[j];
    }
    int gm = m0 + row;
    if (gm < Mc) {
#pragma unroll
        for (int j = 0; j < 8; j++) {
            int col = c8 + j;
            short h, l;
            bsplit(acc[j], h, l);
            if (col < 64) { NAH[gm * 64 + col] = (ushort)h; NAL[gm * 64 + col] = (ushort)l; }
            else { NBH[gm * 64 + col - 64] = (ushort)h; NBL[gm * 64 + col - 64] = (ushort)l; }
        }
    }
}

// ---- adj = sigmoid( (NA NB^T) / 8 ): split-bf16 MFMA, 128-tiles, grid 5x5 -
__global__ __launch_bounds__(256)
void adjmm_k(const ushort* __restrict__ Ah, const ushort* __restrict__ Al,
             const ushort* __restrict__ Bh, const ushort* __restrict__ Bl,
             float* __restrict__ ADJ)
{
    __shared__ __align__(16) ushort As[2][128][40];
    __shared__ __align__(16) ushort Bs[2][128][40];
    const int m0 = blockIdx.y * 128, n0 = blockIdx.x * 128;
    const int t = threadIdx.x;
    const int lane = t & 63, w = t >> 6;
    const int wm = (w >> 1) * 64, wn = (w & 1) * 64;
    const int lm = lane & 15, lq = lane >> 4;

    f32x4 acc[4][4];
#pragma unroll
    for (int i = 0; i < 4; i++)
#pragma unroll
        for (int j = 0; j < 4; j++)
#pragma unroll
            for (int r = 0; r < 4; r++) acc[i][j][r] = 0.f;

    for (int k0 = 0; k0 < 64; k0 += 32) {
        __syncthreads();
#pragma unroll
        for (int p = 0; p < 2; p++) {
            int e = t + p * 256;
            int row = e >> 2, ks = (e & 3) << 3;
            {
                int gm = m0 + row;
                short8 vh, vl;
#pragma unroll
                for (int q = 0; q < 8; q++) { vh[q] = 0; vl[q] = 0; }
                if (gm < Mc) {
                    vh = *(const short8*)(Ah + (long)gm * 64 + k0 + ks);
                    vl = *(const short8*)(Al + (long)gm * 64 + k0 + ks);
                }
                *(short8*)&As[0][row][ks] = vh;
                *(short8*)&As[1][row][ks] = vl;
            }
            {
                int gn = n0 + row;
                short8 vh, vl;
#pragma unroll
                for (int q = 0; q < 8; q++) { vh[q] = 0; vl[q] = 0; }
                if (gn < Mc) {
                    vh = *(const short8*)(Bh + (long)gn * 64 + k0 + ks);
                    vl = *(const short8*)(Bl + (long)gn * 64 + k0 + ks);
                }
                *(short8*)&Bs[0][row][ks] = vh;
                *(short8*)&Bs[1][row][ks] = vl;
            }
        }
        __syncthreads();

        short8 af[4][2], bf[4][2];
#pragma unroll
        for (int i = 0; i < 4; i++) {
            af[i][0] = *(const short8*)&As[0][wm + i * 16 + lm][lq * 8];
            af[i][1] = *(const short8*)&As[1][wm + i * 16 + lm][lq * 8];
        }
#pragma unroll
        for (int j = 0; j < 4; j++) {
            bf[j][0] = *(const short8*)&Bs[0][wn + j * 16 + lm][lq * 8];
            bf[j][1] = *(const short8*)&Bs[1][wn + j * 16 + lm][lq * 8];
        }
#pragma unroll
        for (int i = 0; i < 4; i++)
#pragma unroll
            for (int j = 0; j < 4; j++) {
                acc[i][j] = __builtin_amdgcn_mfma_f32_16x16x32_bf16(af[i][0], bf[j][0], acc[i][j], 0, 0, 0);
                acc[i][j] = __builtin_amdgcn_mfma_f32_16x16x32_bf16(af[i][0], bf[j][1], acc[i][j], 0, 0, 0);
                acc[i][j] = __builtin_amdgcn_mfma_f32_16x16x32_bf16(af[i][1], bf[j][0], acc[i][j], 0, 0, 0);
            }
    }
#pragma unroll
    for (int i = 0; i < 4; i++) {
        int gmb = m0 + wm + i * 16 + lq * 4;
#pragma unroll
        for (int j = 0; j < 4; j++) {
            int gn = n0 + wn + j * 16 + lm;
            if (gn >= Mc) continue;
#pragma unroll
            for (int r = 0; r < 4; r++) {
                int gm = gmb + r;
                if (gm < Mc)
                    ADJ[(long)gm * Mc + gn] = 1.f / (1.f + __expf(-acc[i][j][r] * 0.125f));
            }
        }
    }
}

// ---------------- Wqkv^T prep: transpose + bf16 hi/lo split ----------------
__global__ __launch_bounds__(256)
void wqkv_prep_k(const float* __restrict__ Wqkv,
                 ushort* __restrict__ WQH, ushort* __restrict__ WQL)
{
    int i = blockIdx.x * 256 + threadIdx.x;
    if (i >= 384 * 64) return;
    int n = i >> 6, c = i & 63;
    short h, l;
    bsplit(Wqkv[c * 384 + n], h, l);
    WQH[n * 64 + c] = (ushort)h;
    WQL[n * 64 + c] = (ushort)l;
}

// ---- QKV projection: split-bf16 MFMA, K=64, XCD-swizzled ------------------
__global__ __launch_bounds__(256)
void qkv_mfma_k(const float* __restrict__ CURp,
                const ushort* __restrict__ WQH, const ushort* __restrict__ WQL,
                const float* __restrict__ bias,
                ushort* __restrict__ QH, ushort* __restrict__ QL,
                ushort* __restrict__ KH, ushort* __restrict__ KL,
                ushort* __restrict__ VTH, ushort* __restrict__ VTL)
{
    __shared__ __align__(16) ushort SM[36864];   // 72 KB, multi-purpose
    ushort* AsH = SM;                 // [128][72]
    ushort* AsL = SM + 9216;
    ushort* BsH = SM + 18432;
    ushort* BsL = SM + 27648;
    const int bid = blockIdx.x;
    const int xcd = bid & 7, slot = bid >> 3;
    const int z = (slot / 15) * 8 + xcd;
    const int r15 = slot % 15;
    const int which = r15 % 3;             // 0=q 1=k 2=v
    const int m0 = (r15 / 3) * 128;
    const int nb = which * 128;
    const float* A = CURp + (long)z * Mc * Cc;
    const int t = threadIdx.x;
    const int lane = t & 63, w = t >> 6;
    const int wm = (w >> 1) * 64, wn = (w & 1) * 64;
    const int lm = lane & 15, lq = lane >> 4;

#pragma unroll
    for (int p = 0; p < 8; p++) {
        int e = t + p * 256;              // 0..2047
        int row = e >> 4, k4 = (e & 15) * 4;
        int gm = m0 + row;
        float4 v = make_float4(0.f, 0.f, 0.f, 0.f);
        if (gm < Mc) v = *(const float4*)(A + (long)gm * 64 + k4);
        short4v h4, l4;
        short hs, ls;
        bsplit(v.x, hs, ls); h4[0] = hs; l4[0] = ls;
        bsplit(v.y, hs, ls); h4[1] = hs; l4[1] = ls;
        bsplit(v.z, hs, ls); h4[2] = hs; l4[2] = ls;
        bsplit(v.w, hs, ls); h4[3] = hs; l4[3] = ls;
        *(short4v*)(AsH + row * 72 + k4) = h4;
        *(short4v*)(AsL + row * 72 + k4) = l4;
    }
#pragma unroll
    for (int p = 0; p < 4; p++) {
        int e = t + p * 256;              // 0..1023
        int row = e >> 3, seg = (e & 7) * 8;
        *(short8*)(BsH + row * 72 + seg) = *(const short8*)(WQH + (long)(nb + row) * 64 + seg);
        *(short8*)(BsL + row * 72 + seg) = *(const short8*)(WQL + (long)(nb + row) * 64 + seg);
    }
    __syncthreads();

    f32x4 acc[4][4];
#pragma unroll
    for (int i = 0; i < 4; i++)
#pragma unroll
        for (int j = 0; j < 4; j++)
#pragma unroll
            for (int r = 0; r < 4; r++) acc[i][j][r] = 0.f;

#pragma unroll
    for (int ks = 0; ks < 2; ks++) {
        short8 af[4][2], bf[4][2];
#pragma unroll
        for (int i = 0; i < 4; i++) {
            af[i][0] = *(const short8*)(AsH + (wm + i * 16 + lm) * 72 + ks * 32 + lq * 8);
            af[i][1] = *(const short8*)(AsL + (wm + i * 16 + lm) * 72 + ks * 32 + lq * 8);
        }
#pragma unroll
        for (int j = 0; j < 4; j++) {
            bf[j][0] = *(const short8*)(BsH + (wn + j * 16 + lm) * 72 + ks * 32 + lq * 8);
            bf[j][1] = *(const short8*)(BsL + (wn + j * 16 + lm) * 72 + ks * 32 + lq * 8);
        }
#pragma unroll
        for (int i = 0; i < 4; i++)
#pragma unroll
            for (int j = 0; j < 4; j++) {
                acc[i][j] = __builtin_amdgcn_mfma_f32_16x16x32_bf16(af[i][0], bf[j][0], acc[i][j], 0, 0, 0);
                acc[i][j] = __builtin_amdgcn_mfma_f32_16x16x32_bf16(af[i][0], bf[j][1], acc[i][j], 0, 0, 0);
                acc[i][j] = __builtin_amdgcn_mfma_f32_16x16x32_bf16(af[i][1], bf[j][0], acc[i][j], 0, 0, 0);
            }
    }
    __syncthreads();   // frags consumed; SM reused as C scratch

    uint* CP = (uint*)SM;                 // [128][132] uints
#pragma unroll
    for (int i = 0; i < 4; i++)
#pragma unroll
        for (int j = 0; j < 4; j++) {
            int col = wn + j * 16 + lm;
            float b = bias[nb + col];
#pragma unroll
            for (int r = 0; r < 4; r++) {
                int row = wm + i * 16 + lq * 4 + r;
                float v = acc[i][j][r] + b;
                if (which == 2) v = fmaxf(v, 0.f);
                short hs, ls;
                bsplit(v, hs, ls);
                CP[row * 132 + col] = ((uint)(ushort)ls << 16) | (uint)(ushort)hs;
            }
        }
    __syncthreads();

    if (which == 2) {
        ushort* vh = VTH + (long)z * ATTc * MPAD;
        ushort* vl = VTL + (long)z * ATTc * MPAD;
#pragma unroll
        for (int p = 0; p < 8; p++) {
            int e = t + p * 256;          // 0..2047
            int col = e >> 4, rg = (e & 15) * 8;
            if (m0 + rg < Mc) {
                short8 h8, l8;
#pragma unroll
                for (int q = 0; q < 8; q++) {
                    uint u = CP[(rg + q) * 132 + col];
                    h8[q] = (short)(u & 0xffff);
                    l8[q] = (short)(u >> 16);
                }
                *(short8*)(vh + (long)col * MPAD + m0 + rg) = h8;
                *(short8*)(vl + (long)col * MPAD + m0 + rg) = l8;
            }
        }
    } else {
        ushort* dh = (which == 0 ? QH : KH) + (long)z * Mc * ATTc;
        ushort* dl = (which == 0 ? QL : KL) + (long)z * Mc * ATTc;
#pragma unroll
        for (int p = 0; p < 8; p++) {
            int e = t + p * 256;
            int row = e >> 4, seg = (e & 15) * 8;
            int gm = m0 + row;
            if (gm < Mc) {
                short8 h8, l8;
#pragma unroll
                for (int q = 0; q < 8; q++) {
                    uint u = CP[row * 132 + seg + q];
                    h8[q] = (short)(u & 0xffff);
                    l8[q] = (short)(u >> 16);
                }
                *(short8*)(dh + (long)gm * ATTc + seg) = h8;
                *(short8*)(dl + (long)gm * ATTc + seg) = l8;
            }
        }
    }
}

// ---- fused attention: S=QK^T -> P=exp(s)*adj -> PV ------------------------
// R16: 32x32x16 MFMA shape halves per-wave shared-operand LDS traffic
// (the measured bottleneck). Waves: (qt = w&1) q-tile of 32 rows;
// kh = w>>1 key-half for QK / att-half for PV. P is block-shared LDS
// [64][136] (conflict-free). R14's 4-round reg-prefetch pipeline kept.
#define ISSUE_K(Dh, Dl, kc_, g_)                                        \
  _Pragma("unroll")                                                     \
  for (int p = 0; p < 4; p++) {                                         \
    int key = (kc_) + srow0 + 32 * p;                                   \
    short8 vh, vl;                                                      \
    _Pragma("unroll")                                                   \
    for (int q2 = 0; q2 < 8; q2++) { vh[q2] = 0; vl[q2] = 0; }          \
    if (key < Mc) {                                                     \
      vh = *(const short8*)(Khz + (long)key * ATTc + (g_) * 64 + sks);  \
      vl = *(const short8*)(Klz + (long)key * ATTc + (g_) * 64 + sks);  \
    }                                                                   \
    Dh[p] = vh; Dl[p] = vl;                                             \
  }

#define ISSUE_V(Dh, Dl, kc_, g_)                                                   \
  _Pragma("unroll")                                                                \
  for (int p = 0; p < 4; p++) {                                                    \
    int att = srow0 + 32 * p;                                                      \
    Dh[p] = *(const short8*)(Vhz + (long)att * MPAD + (kc_) + (g_) * 64 + sks);    \
    Dl[p] = *(const short8*)(Vlz + (long)att * MPAD + (kc_) + (g_) * 64 + sks);    \
  }

#define WRITE_SB(Dh, Dl)                                                \
  _Pragma("unroll")                                                     \
  for (int p = 0; p < 4; p++) {                                         \
    *(short8*)&SB[0][srow0 + 32 * p][sks] = Dh[p];                      \
    *(short8*)&SB[1][srow0 + 32 * p][sks] = Dl[p];                      \
  }

#define MFMA32(a, b, c) __builtin_amdgcn_mfma_f32_32x32x16_bf16(a, b, c, 0, 0, 0)

#define QK_ROUND(g_)                                                       \
  _Pragma("unroll")                                                        \
  for (int al = 0; al < 4; al++) {                                         \
    short8 b0h = *(const short8*)&SB[0][kh64 + l31][al * 16 + lh8];        \
    short8 b0l = *(const short8*)&SB[1][kh64 + l31][al * 16 + lh8];        \
    short8 b1h = *(const short8*)&SB[0][kh64 + 32 + l31][al * 16 + lh8];   \
    short8 b1l = *(const short8*)&SB[1][kh64 + 32 + l31][al * 16 + lh8];   \
    s0 = MFMA32(qh[(g_) * 4 + al], b0h, s0);                               \
    s1 = MFMA32(qh[(g_) * 4 + al], b1h, s1);                               \
    s0 = MFMA32(qh[(g_) * 4 + al], b0l, s0);                               \
    s1 = MFMA32(qh[(g_) * 4 + al], b1l, s1);                               \
    s0 = MFMA32(ql[(g_) * 4 + al], b0h, s0);                               \
    s1 = MFMA32(ql[(g_) * 4 + al], b1h, s1);                               \
  }

#define PV_ROUND(g_)                                                       \
  _Pragma("unroll")                                                        \
  for (int kp = 0; kp < 4; kp++) {                                         \
    short8 pA = *(const short8*)&PHs[qt32 + l31][(g_) * 64 + kp * 16 + lh8]; \
    short8 pB = *(const short8*)&PLs[qt32 + l31][(g_) * 64 + kp * 16 + lh8]; \
    short8 v0h = *(const short8*)&SB[0][kh64 + l31][kp * 16 + lh8];        \
    short8 v0l = *(const short8*)&SB[1][kh64 + l31][kp * 16 + lh8];        \
    short8 v1h = *(const short8*)&SB[0][kh64 + 32 + l31][kp * 16 + lh8];   \
    short8 v1l = *(const short8*)&SB[1][kh64 + 32 + l31][kp * 16 + lh8];   \
    o0 = MFMA32(pA, v0h, o0); o1 = MFMA32(pA, v1h, o1);                    \
    o0 = MFMA32(pA, v0l, o0); o1 = MFMA32(pA, v1l, o1);                    \
    o0 = MFMA32(pB, v0h, o0); o1 = MFMA32(pB, v1h, o1);                    \
  }

__global__ __launch_bounds__(256, 2)
void attn_k(const ushort* __restrict__ QH, const ushort* __restrict__ QL,
            const ushort* __restrict__ KH, const ushort* __restrict__ KL,
            const ushort* __restrict__ VTH, const ushort* __restrict__ VTL,
            const float* __restrict__ adj, uint* __restrict__ OB, float scale)
{
    __shared__ __align__(16) ushort SB[2][128][72];   // K or V stage (64 k)
    __shared__ __align__(16) ushort PHs[64][136];     // block-shared P hi
    __shared__ __align__(16) ushort PLs[64][136];     //                lo
    __shared__ float REDs[2][2][2][16];               // [qt][kh][lh][reg]
    __shared__ float REDe[2][2][2][16];
    const int bid = blockIdx.x;
    const int xcd = bid & 7, slot = bid >> 3;
    const int z = (slot / 10) * 8 + xcd;
    const int m0 = (slot % 10) * 64;
    const int t = threadIdx.x;
    const int lane = t & 63, w = t >> 6;
    const int l31 = lane & 31, lh = lane >> 5, lh8 = lh * 8;
    const int qt = w & 1, kh = w >> 1;
    const int qt32 = qt * 32, kh64 = kh * 64;
    const int srow0 = t >> 3;          // staging row base 0..31
    const int sks   = (t & 7) << 3;    // staging col 0..56 (x8 shorts)

    const ushort* Qhz = QH + (long)z * Mc * ATTc;
    const ushort* Qlz = QL + (long)z * Mc * ATTc;
    const ushort* Khz = KH + (long)z * Mc * ATTc;
    const ushort* Klz = KL + (long)z * Mc * ATTc;
    const ushort* Vhz = VTH + (long)z * ATTc * MPAD;
    const ushort* Vlz = VTL + (long)z * ATTc * MPAD;

    // ---- prefetch round 0 (chunk 0, K half0) ----
    short8 RAh[4], RAl[4], RBh[4], RBl[4];
    ISSUE_K(RAh, RAl, 0, 0);

    // ---- Q fragments: 32 q-rows x 128 att, A-layout for 32x32x16 ----
    short8 qh[8], ql[8];
    {
        int qr = m0 + qt32 + l31;
        if (qr < Mc) {
            const ushort* qp  = Qhz + (long)qr * ATTc;
            const ushort* qp2 = Qlz + (long)qr * ATTc;
#pragma unroll
            for (int a = 0; a < 8; a++) {
                qh[a] = *(const short8*)(qp + a * 16 + lh8);
                ql[a] = *(const short8*)(qp2 + a * 16 + lh8);
            }
        } else {
#pragma unroll
            for (int a = 0; a < 8; a++)
#pragma unroll
                for (int q = 0; q < 8; q++) { qh[a][q] = 0; ql[a][q] = 0; }
        }
    }

    f32x16 o0, o1;
#pragma unroll
    for (int r = 0; r < 16; r++) { o0[r] = 0.f; o1[r] = 0.f; }
    float Er[16] = {}, Sr[16] = {};

    for (int c = 0; c < 5; c++) {
        const int kc = c * 128;
        f32x16 s0, s1;
#pragma unroll
        for (int r = 0; r < 16; r++) { s0[r] = 0.f; s1[r] = 0.f; }

        // ---------- round 0: K half0 (atts 0..63) ----------
        __syncthreads();
        WRITE_SB(RAh, RAl);
        ISSUE_K(RBh, RBl, kc, 1);
        __syncthreads();
        QK_ROUND(0);

        // ---------- round 1: K half1 (atts 64..127) ----------
        __syncthreads();
        WRITE_SB(RBh, RBl);
        ISSUE_V(RAh, RAl, kc, 0);
        __syncthreads();
        QK_ROUND(1);

        // ---------- epilogue: P = exp(s*scale)*adj -> shared LDS ----------
        {
            int c0 = kc + kh64 + l31, c1 = c0 + 32;
            bool c0ok = c0 < Mc, c1ok = c1 < Mc;
            float av0[16], av1[16];
#pragma unroll
            for (int r = 0; r < 16; r++) {
                int rl = (r & 3) + 8 * (r >> 2) + 4 * lh;
                int row = m0 + qt32 + rl;
                bool rok = row < Mc;
                av0[r] = (rok && c0ok) ? adj[(long)row * Mc + c0] : 0.f;
                av1[r] = (rok && c1ok) ? adj[(long)row * Mc + c1] : 0.f;
            }
#pragma unroll
            for (int r = 0; r < 16; r++) {
                int rl = (r & 3) + 8 * (r >> 2) + 4 * lh;
                float e0 = c0ok ? __expf(s0[r] * scale) : 0.f;
                float e1 = c1ok ? __expf(s1[r] * scale) : 0.f;
                float p0 = e0 * av0[r], p1 = e1 * av1[r];
                Er[r] += e0 + e1; Sr[r] += p0 + p1;
                short hs, ls;
                bsplit(p0, hs, ls);
                PHs[qt32 + rl][kh64 + l31] = (ushort)hs;
                PLs[qt32 + rl][kh64 + l31] = (ushort)ls;
                bsplit(p1, hs, ls);
                PHs[qt32 + rl][kh64 + 32 + l31] = (ushort)hs;
                PLs[qt32 + rl][kh64 + 32 + l31] = (ushort)ls;
            }
        }

        // ---------- round 2: V half0 (keys 0..63) ----------
        __syncthreads();
        WRITE_SB(RAh, RAl);
        ISSUE_V(RBh, RBl, kc, 1);
        __syncthreads();
        PV_ROUND(0);

        // ---------- round 3: V half1 (keys 64..127) ----------
        __syncthreads();
        WRITE_SB(RBh, RBl);
        if (c < 4) { ISSUE_K(RAh, RAl, kc + 128, 0); }
        __syncthreads();
        PV_ROUND(1);
    }

    // ---- combine per-wave row partials (kh split) and normalize ----
#pragma unroll
    for (int mk = 1; mk <= 16; mk <<= 1)
#pragma unroll
        for (int r = 0; r < 16; r++) {
            Er[r] += __shfl_xor(Er[r], mk, 64);
            Sr[r] += __shfl_xor(Sr[r], mk, 64);
        }
    if (l31 == 0) {
#pragma unroll
        for (int r = 0; r < 16; r++) {
            REDs[qt][kh][lh][r] = Sr[r];
            REDe[qt][kh][lh][r] = Er[r];
        }
    }
    __syncthreads();
    float inv[16];
#pragma unroll
    for (int r = 0; r < 16; r++) {
        float S = REDs[qt][0][lh][r] + REDs[qt][1][lh][r];
        float E = REDe[qt][0][lh][r] + REDe[qt][1][lh][r];
        inv[r] = 1.f / (S + 1e-8f * E);
    }
    uint* Oz = OB + (long)z * Mc * ATTc;
#pragma unroll
    for (int r = 0; r < 16; r++) {
        int rl = (r & 3) + 8 * (r >> 2) + 4 * lh;
        int row = m0 + qt32 + rl;
        if (row < Mc) {
            short hs, ls;
            float v0 = o0[r] * inv[r];
            bsplit(v0, hs, ls);
            Oz[(long)row * ATTc + kh64 + l31] =
                ((uint)(ushort)ls << 16) | (uint)(ushort)hs;
            float v1 = o1[r] * inv[r];
            bsplit(v1, hs, ls);
            Oz[(long)row * ATTc + kh64 + 32 + l31] =
                ((uint)(ushort)ls << 16) | (uint)(ushort)hs;
        }
    }
}

#undef ISSUE_K
#undef ISSUE_V
#undef WRITE_SB
#undef QK_ROUND
#undef PV_ROUND
#undef MFMA32

// ---------------- Wlin^T prep: transpose + bf16 hi/lo split ----------------
__global__ __launch_bounds__(256)
void wlin_prep_k(const float* __restrict__ Wlin,
                 ushort* __restrict__ WTH, ushort* __restrict__ WTL)
{
    int i = blockIdx.x * 256 + threadIdx.x;
    if (i >= 64 * 128) return;
    int c = i >> 7, a = i & 127;
    short h, l;
    bsplit(Wlin[a * 64 + c], h, l);
    WTH[c * 128 + a] = (ushort)h;
    WTL[c * 128 + a] = (ushort)l;
}

// ---- Wlin GEMM: CUR = unpack(OB) @ Wlin + blin; fused cand-max epilogue ---
__global__ __launch_bounds__(256)
void wlin_k(const uint* __restrict__ OB, const ushort* __restrict__ WTH,
            const ushort* __restrict__ WTL, const float* __restrict__ blin,
            float* __restrict__ CUR, int Mtot,
            float* __restrict__ cand, int first)
{
    __shared__ __align__(16) ushort As[2][128][40];
    __shared__ __align__(16) ushort Bs[2][64][136];
    const int m0 = blockIdx.x * 128;
    const int t = threadIdx.x;
    const int lane = t & 63, w = t >> 6;
    const int wm = (w >> 1) * 64, wn = (w & 1) * 32;
    const int lm = lane & 15, lq = lane >> 4;

#pragma unroll
    for (int p = 0; p < 4; p++) {
        int e = t + p * 256;
        int row = e >> 4, seg = (e & 15) << 3;
        *(short8*)&Bs[0][row][seg] = *(const short8*)(WTH + row * 128 + seg);
        *(short8*)&Bs[1][row][seg] = *(const short8*)(WTL + row * 128 + seg);
    }

    f32x4 acc[4][2];
#pragma unroll
    for (int i = 0; i < 4; i++)
#pragma unroll
        for (int j = 0; j < 2; j++)
#pragma unroll
            for (int r = 0; r < 4; r++) acc[i][j][r] = 0.f;

    for (int k0 = 0; k0 < 128; k0 += 32) {
        __syncthreads();
#pragma unroll
        for (int p = 0; p < 2; p++) {
            int e = t + p * 256;
            int row = e >> 2, seg = (e & 3) << 3;
            int gm = m0 + row;
            short8 vh, vl;
#pragma unroll
            for (int q = 0; q < 8; q++) { vh[q] = 0; vl[q] = 0; }
            if (gm < Mtot) {
                const uint4 u0 = *(const uint4*)(OB + (long)gm * 128 + k0 + seg);
                const uint4 u1 = *(const uint4*)(OB + (long)gm * 128 + k0 + seg + 4);
#pragma unroll
                for (int q = 0; q < 4; q++) {
                    uint u = ((const uint*)&u0)[q];
                    vh[q] = (short)(u & 0xffff); vl[q] = (short)(u >> 16);
                }
#pragma unroll
                for (int q = 0; q < 4; q++) {
                    uint u = ((const uint*)&u1)[q];
                    vh[4 + q] = (short)(u & 0xffff); vl[4 + q] = (short)(u >> 16);
                }
            }
            *(short8*)&As[0][row][seg] = vh;
            *(short8*)&As[1][row][seg] = vl;
        }
        __syncthreads();

        short8 af[4][2], bf[2][2];
#pragma unroll
        for (int i = 0; i < 4; i++) {
            af[i][0] = *(const short8*)&As[0][wm + i * 16 + lm][lq * 8];
            af[i][1] = *(const short8*)&As[1][wm + i * 16 + lm][lq * 8];
        }
#pragma unroll
        for (int j = 0; j < 2; j++) {
            bf[j][0] = *(const short8*)&Bs[0][wn + j * 16 + lm][k0 + lq * 8];
            bf[j][1] = *(const short8*)&Bs[1][wn + j * 16 + lm][k0 + lq * 8];
        }
#pragma unroll
        for (int i = 0; i < 4; i++)
#pragma unroll
            for (int j = 0; j < 2; j++) {
                acc[i][j] = __builtin_amdgcn_mfma_f32_16x16x32_bf16(af[i][0], bf[j][0], acc[i][j], 0, 0, 0);
                acc[i][j] = __builtin_amdgcn_mfma_f32_16x16x32_bf16(af[i][0], bf[j][1], acc[i][j], 0, 0, 0);
                acc[i][j] = __builtin_amdgcn_mfma_f32_16x16x32_bf16(af[i][1], bf[j][0], acc[i][j], 0, 0, 0);
            }
    }
#pragma unroll
    for (int i = 0; i < 4; i++) {
        int gmb = m0 + wm + i * 16 + lq * 4;
#pragma unroll
        for (int j = 0; j < 2; j++) {
            int col = wn + j * 16 + lm;
            float b = blin[col];
#pragma unroll
            for (int r = 0; r < 4; r++) {
                int gm = gmb + r;
                if (gm < Mtot) {
                    float v = acc[i][j][r] + b;
                    CUR[(long)gm * 64 + col] = v;
                    int bw = gm / Mc;
                    int m = gm - bw * Mc;
                    if (m >= 2 * Nc) {        // middle-window slice [2N:3N)
                        long o = ((long)bw * Nc + (m - 2 * Nc)) * Cc + col;
                        cand[o] = first ? v : fmaxf(cand[o], v);
                    }
                }
            }
        }
    }
}

// ---------------- output layer ----------------
__global__ __launch_bounds__(128)
void output_k(const float* __restrict__ h2, const float* __restrict__ Wo,
              const float* __restrict__ bo, float* __restrict__ out)
{
    __shared__ float ds[512];
    int row = blockIdx.x;
    int b = row / Nc, n = row % Nc;
    int t = threadIdx.x;
    for (int e = t; e < 512; e += 128) {
        int tt = e >> 6, c = e & 63;
        ds[e] = h2[(((long)b * 8 + tt) * Nc + n) * Cc + c];
    }
    __syncthreads();
    float acc = bo[t];
    for (int e = 0; e < 512; e++) acc += ds[e] * Wo[e * OUTFc + t];
    acc = fmaxf(acc, 0.f);
    for (int p = 0; p < PREDc; p++)
        out[(((long)b * PREDc + p) * Nc + n) * (long)OUTFc + t] = acc;
}

extern "C" void kernel_launch(void* const* d_in, const int* in_sizes, int n_in,
                              void* d_out, int out_size, void* d_ws, size_t ws_size,
                              hipStream_t stream)
{
    (void)in_sizes; (void)n_in; (void)out_size; (void)ws_size;
    const float* x     = (const float*)d_in[0];
    const float* Wqkv  = (const float*)d_in[4];
    const float* bqkv  = (const float*)d_in[5];
    const float* Wlin  = (const float*)d_in[6];
    const float* blin  = (const float*)d_in[7];
    const float* Wa    = (const float*)d_in[8];
    const float* Wb    = (const float*)d_in[9];
    const float* temb0 = (const float*)d_in[13];
    const float* temb1 = (const float*)d_in[14];
    const float* semb  = (const float*)d_in[15];
    const float* Wo    = (const float*)d_in[16];
    const float* bo    = (const float*)d_in[17];
    float* out = (float*)d_out;

    // ---- workspace (float offsets), ~60 MB ----
    float* ws   = (float*)d_ws;
    float* CUR  = ws;                                  // 1,536,000
    float* ADJ  = CUR + (long)MAXBW * Mc * Cc;         // 360,000
    float* CAND = ADJ + (long)Mc * Mc;                 // 512,000
    uint*  OB   = (uint*)(CAND + (long)MAXBW * Nc * Cc); // 3,072,000 u32
    float* QHf  = (float*)(OB + (long)MAXBW * Mc * ATTc);
    const long QSZ = (long)MAXBW * Mc * ATTc / 2;      // in floats
    float* QLf  = QHf + QSZ;
    float* KHf  = QLf + QSZ;
    float* KLf  = KHf + QSZ;
    float* VTHf = KLf + QSZ;
    float* VTLf = VTHf + (long)MAXBW * ATTc * MPAD / 2;
    ushort* NAH = (ushort*)(VTLf + (long)MAXBW * ATTc * MPAD / 2);
    ushort* NAL = NAH + Mc * Cc;
    ushort* NBH = NAL + Mc * Cc;
    ushort* NBL = NBH + Mc * Cc;
    ushort* WTH = NBL + Mc * Cc;                       // 64*128 each
    ushort* WTL = WTH + 64 * 128;
    ushort* WQH = WTL + 64 * 128;                      // 384*64 each
    ushort* WQL = WQH + 384 * 64;

    ushort* QH  = (ushort*)QHf;
    ushort* QL  = (ushort*)QLf;
    ushort* KH  = (ushort*)KHf;
    ushort* KL  = (ushort*)KLf;
    ushort* VTH = (ushort*)VTHf;
    ushort* VTL = (ushort*)VTLf;

    const float inv_sqrt_att = 0.08838834764831845f;   // 1/sqrt(128)

    // weight preps (constant across iterations)
    wlin_prep_k<<<dim3(32), dim3(256), 0, stream>>>(Wlin, WTH, WTL);
    wqkv_prep_k<<<dim3(96), dim3(256), 0, stream>>>(Wqkv, WQH, WQL);

    for (int layer = 0; layer < 2; layer++) {
        int Tin = layer ? 10 : 12;
        int nw  = Tin - 2;
        int BW  = Bc * nw;                             // 40 then 32
        int Mtot = BW * Mc;
        const float* src  = layer ? CAND : x;
        const float* temb = layer ? temb1 : temb0;

        long etotal = (long)BW * Mc * Cc;
        embed_window_k<<<dim3((unsigned)((etotal + 255) / 256)), dim3(256), 0, stream>>>(
            src, temb, semb, CUR, Tin, nw, etotal);

        for (int it = 0; it < 3; it++) {
            // adjacency: mean -> NA/NB (bf16 split) -> sigmoid MFMA
            mean_nab_k<<<dim3(38), dim3(256), 0, stream>>>(
                CUR, Wa, Wb, NAH, NAL, NBH, NBL, BW);
            adjmm_k<<<dim3(5, 5), dim3(256), 0, stream>>>(
                NAH, NAL, NBH, NBL, ADJ);

            // QKV projection (split-bf16 MFMA, XCD-swizzled)
            qkv_mfma_k<<<dim3(BW * 15), dim3(256), 0, stream>>>(
                CUR, WQH, WQL, bqkv, QH, QL, KH, KL, VTH, VTL);

            // fused attention (R16: 32x32 MFMA, pipelined)
            attn_k<<<dim3(BW * 10), dim3(256), 0, stream>>>(
                QH, QL, KH, KL, VTH, VTL, ADJ, OB, inv_sqrt_att);

            // cur = O @ Wlin + blin, with fused middle-window running max
            wlin_k<<<dim3((Mtot + 127) / 128), dim3(256), 0, stream>>>(
                OB, WTH, WTL, blin, CUR, Mtot, CAND, it == 0 ? 1 : 0);
        }
    }
    output_k<<<dim3(Bc * Nc), dim3(128), 0, stream>>>(CAND, Wo, bo, out);
}

// Round 4
// 797.958 us; speedup vs baseline: 1.8175x; 1.2815x over previous
//
#include <hip/hip_runtime.h>
#include <hip/hip_bf16.h>
#include <math.h>

constexpr int Bc   = 4;
constexpr int Nc   = 200;
constexpr int Cc   = 64;
constexpr int Mc   = 600;    // 3*N
constexpr int ATTc = 128;
constexpr int OUTFc = 128;
constexpr int PREDc = 12;
constexpr int MAXBW = 40;
constexpr int MPAD  = 640;   // padded V^T leading dim

typedef short short4v __attribute__((ext_vector_type(4)));
typedef short short8 __attribute__((ext_vector_type(8)));
typedef float f32x4  __attribute__((ext_vector_type(4)));

static __device__ __forceinline__ void bsplit(float v, short& h, short& l) {
    __hip_bfloat16 hb = __float2bfloat16(v);
    float hf = __bfloat162float(hb);
    __hip_bfloat16 lb = __float2bfloat16(v - hf);
    h = *(short*)&hb; l = *(short*)&lb;
}

// ---------------- embed + sliding window ----------------
__global__ __launch_bounds__(256)
void embed_window_k(const float* __restrict__ src, const float* __restrict__ temb,
                    const float* __restrict__ semb, float* __restrict__ dst,
                    int Tin, int nw, long total)
{
    long idx = (long)blockIdx.x * 256 + threadIdx.x;
    if (idx >= total) return;
    int c = (int)(idx & 63);
    long r = idx >> 6;
    int n = (int)(r % Nc); r /= Nc;
    int j = (int)(r % 3);  r /= 3;
    int w = (int)(r % nw);
    int b = (int)(r / nw);
    int t = w + j;
    dst[idx] = src[(((long)b * Tin + t) * Nc + n) * Cc + c]
             + temb[t * Cc + c] + semb[n * Cc + c];
}

// ------- fused node-mean + NA/NB projection -> bf16 hi/lo outputs ---------
__global__ __launch_bounds__(256)
void mean_nab_k(const float* __restrict__ cur, const float* __restrict__ Wa,
                const float* __restrict__ Wb,
                ushort* __restrict__ NAH, ushort* __restrict__ NAL,
                ushort* __restrict__ NBH, ushort* __restrict__ NBL, int BW)
{
    __shared__ float Ns[64][17];   // [k][row]
    __shared__ float Ws[64][132];  // [k][ Wa | Wb ]
    const int m0 = blockIdx.x * 16;
    const int t = threadIdx.x;
    for (int e = t; e < 1024; e += 256) {
        int r = e >> 4, c4 = (e & 15) << 2;
        *(float4*)&Ws[r][c4]      = *(const float4*)&Wa[r * 64 + c4];
        *(float4*)&Ws[r][64 + c4] = *(const float4*)&Wb[r * 64 + c4];
    }
    {
        int row = t >> 4, c4 = (t & 15) << 2;
        int gm = m0 + row;
        float4 sv = make_float4(0.f, 0.f, 0.f, 0.f);
        if (gm < Mc) {
            for (int bw = 0; bw < BW; bw++) {
                const float4 v = *(const float4*)&cur[((long)bw * Mc + gm) * Cc + c4];
                sv.x += v.x; sv.y += v.y; sv.z += v.z; sv.w += v.w;
            }
        }
        const float inv = 1.f / BW;
        Ns[c4 + 0][row] = sv.x * inv; Ns[c4 + 1][row] = sv.y * inv;
        Ns[c4 + 2][row] = sv.z * inv; Ns[c4 + 3][row] = sv.w * inv;
    }
    __syncthreads();
    const int row = t >> 4, c8 = (t & 15) * 8;
    float acc[8] = {};
    for (int k = 0; k < 64; k++) {
        float a = Ns[k][row];
        float b[8];
        *(float4*)&b[0] = *(const float4*)&Ws[k][c8];
        *(float4*)&b[4] = *(const float4*)&Ws[k][c8 + 4];
#pragma unroll
        for (int j = 0; j < 8; j++) acc[j] += a * b[j];
    }
    int gm = m0 + row;
    if (gm < Mc) {
#pragma unroll
        for (int j = 0; j < 8; j++) {
            int col = c8 + j;
            short h, l;
            bsplit(acc[j], h, l);
            if (col < 64) { NAH[gm * 64 + col] = (ushort)h; NAL[gm * 64 + col] = (ushort)l; }
            else { NBH[gm * 64 + col - 64] = (ushort)h; NBL[gm * 64 + col - 64] = (ushort)l; }
        }
    }
}

// ---- adj = sigmoid( (NA NB^T) / 8 ): split-bf16 MFMA, 128-tiles, grid 5x5 -
__global__ __launch_bounds__(256)
void adjmm_k(const ushort* __restrict__ Ah, const ushort* __restrict__ Al,
             const ushort* __restrict__ Bh, const ushort* __restrict__ Bl,
             float* __restrict__ ADJ)
{
    __shared__ __align__(16) ushort As[2][128][40];
    __shared__ __align__(16) ushort Bs[2][128][40];
    const int m0 = blockIdx.y * 128, n0 = blockIdx.x * 128;
    const int t = threadIdx.x;
    const int lane = t & 63, w = t >> 6;
    const int wm = (w >> 1) * 64, wn = (w & 1) * 64;
    const int lm = lane & 15, lq = lane >> 4;

    f32x4 acc[4][4];
#pragma unroll
    for (int i = 0; i < 4; i++)
#pragma unroll
        for (int j = 0; j < 4; j++)
#pragma unroll
            for (int r = 0; r < 4; r++) acc[i][j][r] = 0.f;

    for (int k0 = 0; k0 < 64; k0 += 32) {
        __syncthreads();
#pragma unroll
        for (int p = 0; p < 2; p++) {
            int e = t + p * 256;
            int row = e >> 2, ks = (e & 3) << 3;
            {
                int gm = m0 + row;
                short8 vh, vl;
#pragma unroll
                for (int q = 0; q < 8; q++) { vh[q] = 0; vl[q] = 0; }
                if (gm < Mc) {
                    vh = *(const short8*)(Ah + (long)gm * 64 + k0 + ks);
                    vl = *(const short8*)(Al + (long)gm * 64 + k0 + ks);
                }
                *(short8*)&As[0][row][ks] = vh;
                *(short8*)&As[1][row][ks] = vl;
            }
            {
                int gn = n0 + row;
                short8 vh, vl;
#pragma unroll
                for (int q = 0; q < 8; q++) { vh[q] = 0; vl[q] = 0; }
                if (gn < Mc) {
                    vh = *(const short8*)(Bh + (long)gn * 64 + k0 + ks);
                    vl = *(const short8*)(Bl + (long)gn * 64 + k0 + ks);
                }
                *(short8*)&Bs[0][row][ks] = vh;
                *(short8*)&Bs[1][row][ks] = vl;
            }
        }
        __syncthreads();

        short8 af[4][2], bf[4][2];
#pragma unroll
        for (int i = 0; i < 4; i++) {
            af[i][0] = *(const short8*)&As[0][wm + i * 16 + lm][lq * 8];
            af[i][1] = *(const short8*)&As[1][wm + i * 16 + lm][lq * 8];
        }
#pragma unroll
        for (int j = 0; j < 4; j++) {
            bf[j][0] = *(const short8*)&Bs[0][wn + j * 16 + lm][lq * 8];
            bf[j][1] = *(const short8*)&Bs[1][wn + j * 16 + lm][lq * 8];
        }
#pragma unroll
        for (int i = 0; i < 4; i++)
#pragma unroll
            for (int j = 0; j < 4; j++) {
                acc[i][j] = __builtin_amdgcn_mfma_f32_16x16x32_bf16(af[i][0], bf[j][0], acc[i][j], 0, 0, 0);
                acc[i][j] = __builtin_amdgcn_mfma_f32_16x16x32_bf16(af[i][0], bf[j][1], acc[i][j], 0, 0, 0);
                acc[i][j] = __builtin_amdgcn_mfma_f32_16x16x32_bf16(af[i][1], bf[j][0], acc[i][j], 0, 0, 0);
            }
    }
#pragma unroll
    for (int i = 0; i < 4; i++) {
        int gmb = m0 + wm + i * 16 + lq * 4;
#pragma unroll
        for (int j = 0; j < 4; j++) {
            int gn = n0 + wn + j * 16 + lm;
            if (gn >= Mc) continue;
#pragma unroll
            for (int r = 0; r < 4; r++) {
                int gm = gmb + r;
                if (gm < Mc)
                    ADJ[(long)gm * Mc + gn] = 1.f / (1.f + __expf(-acc[i][j][r] * 0.125f));
            }
        }
    }
}

// ---------------- Wqkv^T prep: transpose + bf16 hi/lo split ----------------
__global__ __launch_bounds__(256)
void wqkv_prep_k(const float* __restrict__ Wqkv,
                 ushort* __restrict__ WQH, ushort* __restrict__ WQL)
{
    int i = blockIdx.x * 256 + threadIdx.x;
    if (i >= 384 * 64) return;
    int n = i >> 6, c = i & 63;
    short h, l;
    bsplit(Wqkv[c * 384 + n], h, l);
    WQH[n * 64 + c] = (ushort)h;
    WQL[n * 64 + c] = (ushort)l;
}

// ---- QKV projection: split-bf16 MFMA, K=64, XCD-swizzled ------------------
// R17: B (WqkvT) read direct from global (L2-hot 96 KB constant) -> no Bs
// stage; packed-C LDS scratch processed in two 64-col halves overlapping the
// retired A-stage -> LDS 72->36 KB -> 3 blocks/CU.
__global__ __launch_bounds__(256)
void qkv_mfma_k(const float* __restrict__ CURp,
                const ushort* __restrict__ WQH, const ushort* __restrict__ WQL,
                const float* __restrict__ bias,
                ushort* __restrict__ QH, ushort* __restrict__ QL,
                ushort* __restrict__ KH, ushort* __restrict__ KL,
                ushort* __restrict__ VTH, ushort* __restrict__ VTL)
{
    __shared__ __align__(16) ushort SM[18432];   // 36 KB, multi-purpose
    ushort* AsH = SM;                 // [128][72]
    ushort* AsL = SM + 9216;
    const int bid = blockIdx.x;
    const int xcd = bid & 7, slot = bid >> 3;
    const int z = (slot / 15) * 8 + xcd;
    const int r15 = slot % 15;
    const int which = r15 % 3;             // 0=q 1=k 2=v
    const int m0 = (r15 / 3) * 128;
    const int nb = which * 128;
    const float* A = CURp + (long)z * Mc * Cc;
    const int t = threadIdx.x;
    const int lane = t & 63, w = t >> 6;
    const int wm = (w >> 1) * 64, wn = (w & 1) * 64;
    const int lm = lane & 15, lq = lane >> 4;

    // ---- stage A: CUR tile 128 rows x 64 k, fp32 -> hi/lo ----
#pragma unroll
    for (int p = 0; p < 8; p++) {
        int e = t + p * 256;              // 0..2047
        int row = e >> 4, k4 = (e & 15) * 4;
        int gm = m0 + row;
        float4 v = make_float4(0.f, 0.f, 0.f, 0.f);
        if (gm < Mc) v = *(const float4*)(A + (long)gm * 64 + k4);
        short4v h4, l4;
        short hs, ls;
        bsplit(v.x, hs, ls); h4[0] = hs; l4[0] = ls;
        bsplit(v.y, hs, ls); h4[1] = hs; l4[1] = ls;
        bsplit(v.z, hs, ls); h4[2] = hs; l4[2] = ls;
        bsplit(v.w, hs, ls); h4[3] = hs; l4[3] = ls;
        *(short4v*)(AsH + row * 72 + k4) = h4;
        *(short4v*)(AsL + row * 72 + k4) = l4;
    }
    __syncthreads();

    f32x4 acc[4][4];
#pragma unroll
    for (int i = 0; i < 4; i++)
#pragma unroll
        for (int j = 0; j < 4; j++)
#pragma unroll
            for (int r = 0; r < 4; r++) acc[i][j][r] = 0.f;

#pragma unroll
    for (int ks = 0; ks < 2; ks++) {
        short8 af[4][2], bf[4][2];
#pragma unroll
        for (int j = 0; j < 4; j++) {           // B direct from global
            const long brow = nb + wn + j * 16 + lm;
            bf[j][0] = *(const short8*)(WQH + brow * 64 + ks * 32 + lq * 8);
            bf[j][1] = *(const short8*)(WQL + brow * 64 + ks * 32 + lq * 8);
        }
#pragma unroll
        for (int i = 0; i < 4; i++) {
            af[i][0] = *(const short8*)(AsH + (wm + i * 16 + lm) * 72 + ks * 32 + lq * 8);
            af[i][1] = *(const short8*)(AsL + (wm + i * 16 + lm) * 72 + ks * 32 + lq * 8);
        }
#pragma unroll
        for (int i = 0; i < 4; i++)
#pragma unroll
            for (int j = 0; j < 4; j++) {
                acc[i][j] = __builtin_amdgcn_mfma_f32_16x16x32_bf16(af[i][0], bf[j][0], acc[i][j], 0, 0, 0);
                acc[i][j] = __builtin_amdgcn_mfma_f32_16x16x32_bf16(af[i][0], bf[j][1], acc[i][j], 0, 0, 0);
                acc[i][j] = __builtin_amdgcn_mfma_f32_16x16x32_bf16(af[i][1], bf[j][0], acc[i][j], 0, 0, 0);
            }
    }
    __syncthreads();   // frags consumed; SM reused as C scratch

    // ---- C -> packed (hi|lo) uint LDS scratch, two 64-col halves ----
    uint* CP = (uint*)SM;                 // [128][66] uints = 33.8 KB
#pragma unroll
    for (int half = 0; half < 2; half++) {
        if ((w & 1) == half) {            // this wave's wn covers the half
#pragma unroll
            for (int i = 0; i < 4; i++)
#pragma unroll
                for (int j = 0; j < 4; j++) {
                    int col = wn + j * 16 + lm;
                    int lc  = col - half * 64;        // 0..63
                    float b = bias[nb + col];
#pragma unroll
                    for (int r = 0; r < 4; r++) {
                        int row = wm + i * 16 + lq * 4 + r;
                        float v = acc[i][j][r] + b;
                        if (which == 2) v = fmaxf(v, 0.f);
                        short hs, ls;
                        bsplit(v, hs, ls);
                        CP[row * 66 + lc] = ((uint)(ushort)ls << 16) | (uint)(ushort)hs;
                    }
                }
        }
        __syncthreads();

        if (which == 2) {
            // V: transposed packed store [att-col][MPAD] + row
            ushort* vh = VTH + (long)z * ATTc * MPAD;
            ushort* vl = VTL + (long)z * ATTc * MPAD;
#pragma unroll
            for (int p = 0; p < 4; p++) {
                int e = t + p * 256;      // 0..1023
                int col = e >> 4, rg = (e & 15) * 8;   // col 0..63, rg 0..120
                if (m0 + rg < Mc) {
                    short8 h8, l8;
#pragma unroll
                    for (int q = 0; q < 8; q++) {
                        uint u = CP[(rg + q) * 66 + col];
                        h8[q] = (short)(u & 0xffff);
                        l8[q] = (short)(u >> 16);
                    }
                    int gcol = half * 64 + col;
                    *(short8*)(vh + (long)gcol * MPAD + m0 + rg) = h8;
                    *(short8*)(vl + (long)gcol * MPAD + m0 + rg) = l8;
                }
            }
        } else {
            // Q/K: row-major packed store [row][128], this half's 64 cols
            ushort* dh = (which == 0 ? QH : KH) + (long)z * Mc * ATTc;
            ushort* dl = (which == 0 ? QL : KL) + (long)z * Mc * ATTc;
#pragma unroll
            for (int p = 0; p < 4; p++) {
                int e = t + p * 256;      // 0..1023
                int row = e >> 3, seg = (e & 7) * 8;   // row 0..127, seg 0..56
                int gm = m0 + row;
                if (gm < Mc) {
                    short8 h8, l8;
#pragma unroll
                    for (int q = 0; q < 8; q++) {
                        uint u = CP[row * 66 + seg + q];
                        h8[q] = (short)(u & 0xffff);
                        l8[q] = (short)(u >> 16);
                    }
                    *(short8*)(dh + (long)gm * ATTc + half * 64 + seg) = h8;
                    *(short8*)(dl + (long)gm * ATTc + half * 64 + seg) = l8;
                }
            }
        }
        __syncthreads();                  // before next half overwrites CP
    }
}

// ---- fused attention (R14-proven): S=QK^T -> P=exp(s)*adj -> PV -----------
// Grid BW*10 XCD-swizzled, 64 q-rows/block, 4 waves x 16 rows, K/V LDS-staged,
// P wave-private. Software-pipelined staging (T14 async split): each round
// writes prefetched regs -> LDS, issues the NEXT round's loads, then MFMAs.
#define ISSUE_K(Dh, Dl, kc_, g_)                                        \
  _Pragma("unroll")                                                     \
  for (int p = 0; p < 4; p++) {                                         \
    int key = (kc_) + srow0 + 32 * p;                                   \
    short8 vh, vl;                                                      \
    _Pragma("unroll")                                                   \
    for (int q2 = 0; q2 < 8; q2++) { vh[q2] = 0; vl[q2] = 0; }          \
    if (key < Mc) {                                                     \
      vh = *(const short8*)(Khz + (long)key * ATTc + (g_) * 64 + sks);  \
      vl = *(const short8*)(Klz + (long)key * ATTc + (g_) * 64 + sks);  \
    }                                                                   \
    Dh[p] = vh; Dl[p] = vl;                                             \
  }

#define ISSUE_V(Dh, Dl, kc_, g_)                                                   \
  _Pragma("unroll")                                                                \
  for (int p = 0; p < 4; p++) {                                                    \
    int att = srow0 + 32 * p;                                                      \
    Dh[p] = *(const short8*)(Vhz + (long)att * MPAD + (kc_) + (g_) * 64 + sks);    \
    Dl[p] = *(const short8*)(Vlz + (long)att * MPAD + (kc_) + (g_) * 64 + sks);    \
  }

#define WRITE_SB(Dh, Dl)                                                \
  _Pragma("unroll")                                                     \
  for (int p = 0; p < 4; p++) {                                         \
    *(short8*)&SB[0][srow0 + 32 * p][sks] = Dh[p];                      \
    *(short8*)&SB[1][srow0 + 32 * p][sks] = Dl[p];                      \
  }

#define MFMA_QK(base_)                                                   \
  _Pragma("unroll")                                                      \
  for (int kk = 0; kk < 2; kk++) {                                       \
    _Pragma("unroll")                                                    \
    for (int j = 0; j < 8; j++) {                                        \
      short8 bh = *(const short8*)&SB[0][j * 16 + lm][kk * 32 + lq * 8]; \
      short8 bl = *(const short8*)&SB[1][j * 16 + lm][kk * 32 + lq * 8]; \
      sacc[j] = __builtin_amdgcn_mfma_f32_16x16x32_bf16(qh[(base_) + kk], bh, sacc[j], 0, 0, 0); \
      sacc[j] = __builtin_amdgcn_mfma_f32_16x16x32_bf16(qh[(base_) + kk], bl, sacc[j], 0, 0, 0); \
      sacc[j] = __builtin_amdgcn_mfma_f32_16x16x32_bf16(ql[(base_) + kk], bh, sacc[j], 0, 0, 0); \
    }                                                                    \
  }

#define MFMA_PV(g_)                                                      \
  _Pragma("unroll")                                                      \
  for (int kk = 0; kk < 2; kk++) {                                       \
    int po = ((g_) * 64 + kk * 32 + lq * 8) ^ ((lm >> 2) << 3);          \
    short8 ph = *(const short8*)&PH[w][lm][po];                          \
    short8 pl = *(const short8*)&PL[w][lm][po];                          \
    _Pragma("unroll")                                                    \
    for (int j = 0; j < 8; j++) {                                        \
      short8 vh = *(const short8*)&SB[0][j * 16 + lm][kk * 32 + lq * 8]; \
      short8 vl = *(const short8*)&SB[1][j * 16 + lm][kk * 32 + lq * 8]; \
      oacc[j] = __builtin_amdgcn_mfma_f32_16x16x32_bf16(ph, vh, oacc[j], 0, 0, 0); \
      oacc[j] = __builtin_amdgcn_mfma_f32_16x16x32_bf16(ph, vl, oacc[j], 0, 0, 0); \
      oacc[j] = __builtin_amdgcn_mfma_f32_16x16x32_bf16(pl, vh, oacc[j], 0, 0, 0); \
    }                                                                    \
  }

__global__ __launch_bounds__(256, 2)
void attn_k(const ushort* __restrict__ QH, const ushort* __restrict__ QL,
            const ushort* __restrict__ KH, const ushort* __restrict__ KL,
            const ushort* __restrict__ VTH, const ushort* __restrict__ VTL,
            const float* __restrict__ adj, uint* __restrict__ OB, float scale)
{
    __shared__ __align__(16) ushort SB[2][128][72];   // K or V stage (64 k)
    __shared__ __align__(16) ushort PH[4][16][152];   // wave-private P hi
    __shared__ __align__(16) ushort PL[4][16][152];   //                lo
    const int bid = blockIdx.x;
    const int xcd = bid & 7, slot = bid >> 3;
    const int z = (slot / 10) * 8 + xcd;
    const int m0 = (slot % 10) * 64;
    const int t = threadIdx.x;
    const int lane = t & 63, w = t >> 6;
    const int lm = lane & 15, lq = lane >> 4;
    const int qrow0 = m0 + w * 16;
    const int srow0 = t >> 3;          // staging row base 0..31
    const int sks   = (t & 7) << 3;    // staging col 0..56 (x8 shorts)

    const ushort* Qhz = QH + (long)z * Mc * ATTc;
    const ushort* Qlz = QL + (long)z * Mc * ATTc;
    const ushort* Khz = KH + (long)z * Mc * ATTc;
    const ushort* Klz = KL + (long)z * Mc * ATTc;
    const ushort* Vhz = VTH + (long)z * ATTc * MPAD;
    const ushort* Vlz = VTL + (long)z * ATTc * MPAD;

    // ---- prefetch round 0 (chunk 0, K half0) ----
    short8 RAh[4], RAl[4], RBh[4], RBl[4];
    ISSUE_K(RAh, RAl, 0, 0);

    // ---- Q fragments ----
    short8 qh[4], ql[4];
    {
        int qr = qrow0 + lm;
        if (qr < Mc) {
            const ushort* qp = Qhz + (long)qr * ATTc;
            const ushort* qp2 = Qlz + (long)qr * ATTc;
#pragma unroll
            for (int ks = 0; ks < 4; ks++) {
                qh[ks] = *(const short8*)(qp + ks * 32 + lq * 8);
                ql[ks] = *(const short8*)(qp2 + ks * 32 + lq * 8);
            }
        } else {
#pragma unroll
            for (int ks = 0; ks < 4; ks++)
#pragma unroll
                for (int q = 0; q < 8; q++) { qh[ks][q] = 0; ql[ks][q] = 0; }
        }
    }

    f32x4 oacc[8];
#pragma unroll
    for (int j = 0; j < 8; j++)
#pragma unroll
        for (int r = 0; r < 4; r++) oacc[j][r] = 0.f;
    float Er[4] = {}, Sr[4] = {};
    float adjv[8][4];

    for (int c = 0; c < 5; c++) {
        const int kc = c * 128;
        f32x4 sacc[8];
#pragma unroll
        for (int j = 0; j < 8; j++)
#pragma unroll
            for (int r = 0; r < 4; r++) sacc[j][r] = 0.f;

        // ---------- round 0: K half0 ----------
        __syncthreads();
        WRITE_SB(RAh, RAl);
        ISSUE_K(RBh, RBl, kc, 1);
        // prefetch this chunk's adj block into regs (consumed 2 phases later)
#pragma unroll
        for (int j = 0; j < 8; j++) {
            int col = kc + j * 16 + lm;
#pragma unroll
            for (int r = 0; r < 4; r++) {
                int row = qrow0 + lq * 4 + r;
                adjv[j][r] = (col < Mc && row < Mc) ? adj[(long)row * Mc + col] : 0.f;
            }
        }
        __syncthreads();
        MFMA_QK(0);

        // ---------- round 1: K half1 ----------
        __syncthreads();
        WRITE_SB(RBh, RBl);
        ISSUE_V(RAh, RAl, kc, 0);
        __syncthreads();
        MFMA_QK(2);

        // ---------- epilogue: P = exp(s*scale)*adj -> wave-private LDS ----
#pragma unroll
        for (int j = 0; j < 8; j++) {
            int col = kc + j * 16 + lm;
            bool cok = col < Mc;
#pragma unroll
            for (int r = 0; r < 4; r++) {
                float e = cok ? __expf(sacc[j][r] * scale) : 0.f;
                float p = e * adjv[j][r];
                Er[r] += e; Sr[r] += p;
                short hs, ls;
                bsplit(p, hs, ls);
                int cs = (j * 16 + lm) ^ (lq << 3);   // row>>2 == lq swizzle
                PH[w][lq * 4 + r][cs] = (ushort)hs;
                PL[w][lq * 4 + r][cs] = (ushort)ls;
            }
        }

        // ---------- round 2: V half0 ----------
        __syncthreads();
        WRITE_SB(RAh, RAl);
        ISSUE_V(RBh, RBl, kc, 1);
        __syncthreads();
        MFMA_PV(0);

        // ---------- round 3: V half1 ----------
        __syncthreads();
        WRITE_SB(RBh, RBl);
        if (c < 4) { ISSUE_K(RAh, RAl, kc + 128, 0); }
        __syncthreads();
        MFMA_PV(1);
    }

    // ---- row sums, then packed bf16 hi/lo store ----
#pragma unroll
    for (int mk = 1; mk <= 8; mk <<= 1)
#pragma unroll
        for (int r = 0; r < 4; r++) {
            Er[r] += __shfl_xor(Er[r], mk, 64);
            Sr[r] += __shfl_xor(Sr[r], mk, 64);
        }
    float inv[4];
#pragma unroll
    for (int r = 0; r < 4; r++) inv[r] = 1.f / (Sr[r] + 1e-8f * Er[r]);
    uint* Oz = OB + (long)z * Mc * ATTc;
#pragma unroll
    for (int j = 0; j < 8; j++)
#pragma unroll
        for (int r = 0; r < 4; r++) {
            int row = qrow0 + lq * 4 + r;
            if (row < Mc) {
                float v = oacc[j][r] * inv[r];
                short hs, ls;
                bsplit(v, hs, ls);
                Oz[(long)row * ATTc + j * 16 + lm] =
                    ((uint)(ushort)ls << 16) | (uint)(ushort)hs;
            }
        }
}

#undef ISSUE_K
#undef ISSUE_V
#undef WRITE_SB
#undef MFMA_QK
#undef MFMA_PV

// ---------------- Wlin^T prep: transpose + bf16 hi/lo split ----------------
__global__ __launch_bounds__(256)
void wlin_prep_k(const float* __restrict__ Wlin,
                 ushort* __restrict__ WTH, ushort* __restrict__ WTL)
{
    int i = blockIdx.x * 256 + threadIdx.x;
    if (i >= 64 * 128) return;
    int c = i >> 7, a = i & 127;
    short h, l;
    bsplit(Wlin[a * 64 + c], h, l);
    WTH[c * 128 + a] = (ushort)h;
    WTL[c * 128 + a] = (ushort)l;
}

// ---- Wlin GEMM: CUR = unpack(OB) @ Wlin + blin; fused cand-max epilogue ---
__global__ __launch_bounds__(256)
void wlin_k(const uint* __restrict__ OB, const ushort* __restrict__ WTH,
            const ushort* __restrict__ WTL, const float* __restrict__ blin,
            float* __restrict__ CUR, int Mtot,
            float* __restrict__ cand, int first)
{
    __shared__ __align__(16) ushort As[2][128][40];
    __shared__ __align__(16) ushort Bs[2][64][136];
    const int m0 = blockIdx.x * 128;
    const int t = threadIdx.x;
    const int lane = t & 63, w = t >> 6;
    const int wm = (w >> 1) * 64, wn = (w & 1) * 32;
    const int lm = lane & 15, lq = lane >> 4;

#pragma unroll
    for (int p = 0; p < 4; p++) {
        int e = t + p * 256;
        int row = e >> 4, seg = (e & 15) << 3;
        *(short8*)&Bs[0][row][seg] = *(const short8*)(WTH + row * 128 + seg);
        *(short8*)&Bs[1][row][seg] = *(const short8*)(WTL + row * 128 + seg);
    }

    f32x4 acc[4][2];
#pragma unroll
    for (int i = 0; i < 4; i++)
#pragma unroll
        for (int j = 0; j < 2; j++)
#pragma unroll
            for (int r = 0; r < 4; r++) acc[i][j][r] = 0.f;

    for (int k0 = 0; k0 < 128; k0 += 32) {
        __syncthreads();
#pragma unroll
        for (int p = 0; p < 2; p++) {
            int e = t + p * 256;
            int row = e >> 2, seg = (e & 3) << 3;
            int gm = m0 + row;
            short8 vh, vl;
#pragma unroll
            for (int q = 0; q < 8; q++) { vh[q] = 0; vl[q] = 0; }
            if (gm < Mtot) {
                const uint4 u0 = *(const uint4*)(OB + (long)gm * 128 + k0 + seg);
                const uint4 u1 = *(const uint4*)(OB + (long)gm * 128 + k0 + seg + 4);
#pragma unroll
                for (int q = 0; q < 4; q++) {
                    uint u = ((const uint*)&u0)[q];
                    vh[q] = (short)(u & 0xffff); vl[q] = (short)(u >> 16);
                }
#pragma unroll
                for (int q = 0; q < 4; q++) {
                    uint u = ((const uint*)&u1)[q];
                    vh[4 + q] = (short)(u & 0xffff); vl[4 + q] = (short)(u >> 16);
                }
            }
            *(short8*)&As[0][row][seg] = vh;
            *(short8*)&As[1][row][seg] = vl;
        }
        __syncthreads();

        short8 af[4][2], bf[2][2];
#pragma unroll
        for (int i = 0; i < 4; i++) {
            af[i][0] = *(const short8*)&As[0][wm + i * 16 + lm][lq * 8];
            af[i][1] = *(const short8*)&As[1][wm + i * 16 + lm][lq * 8];
        }
#pragma unroll
        for (int j = 0; j < 2; j++) {
            bf[j][0] = *(const short8*)&Bs[0][wn + j * 16 + lm][k0 + lq * 8];
            bf[j][1] = *(const short8*)&Bs[1][wn + j * 16 + lm][k0 + lq * 8];
        }
#pragma unroll
        for (int i = 0; i < 4; i++)
#pragma unroll
            for (int j = 0; j < 2; j++) {
                acc[i][j] = __builtin_amdgcn_mfma_f32_16x16x32_bf16(af[i][0], bf[j][0], acc[i][j], 0, 0, 0);
                acc[i][j] = __builtin_amdgcn_mfma_f32_16x16x32_bf16(af[i][0], bf[j][1], acc[i][j], 0, 0, 0);
                acc[i][j] = __builtin_amdgcn_mfma_f32_16x16x32_bf16(af[i][1], bf[j][0], acc[i][j], 0, 0, 0);
            }
    }
#pragma unroll
    for (int i = 0; i < 4; i++) {
        int gmb = m0 + wm + i * 16 + lq * 4;
#pragma unroll
        for (int j = 0; j < 2; j++) {
            int col = wn + j * 16 + lm;
            float b = blin[col];
#pragma unroll
            for (int r = 0; r < 4; r++) {
                int gm = gmb + r;
                if (gm < Mtot) {
                    float v = acc[i][j][r] + b;
                    CUR[(long)gm * 64 + col] = v;
                    int bw = gm / Mc;
                    int m = gm - bw * Mc;
                    if (m >= 2 * Nc) {        // middle-window slice [2N:3N)
                        long o = ((long)bw * Nc + (m - 2 * Nc)) * Cc + col;
                        cand[o] = first ? v : fmaxf(cand[o], v);
                    }
                }
            }
        }
    }
}

// ---------------- output layer ----------------
__global__ __launch_bounds__(128)
void output_k(const float* __restrict__ h2, const float* __restrict__ Wo,
              const float* __restrict__ bo, float* __restrict__ out)
{
    __shared__ float ds[512];
    int row = blockIdx.x;
    int b = row / Nc, n = row % Nc;
    int t = threadIdx.x;
    for (int e = t; e < 512; e += 128) {
        int tt = e >> 6, c = e & 63;
        ds[e] = h2[(((long)b * 8 + tt) * Nc + n) * Cc + c];
    }
    __syncthreads();
    float acc = bo[t];
    for (int e = 0; e < 512; e++) acc += ds[e] * Wo[e * OUTFc + t];
    acc = fmaxf(acc, 0.f);
    for (int p = 0; p < PREDc; p++)
        out[(((long)b * PREDc + p) * Nc + n) * (long)OUTFc + t] = acc;
}

extern "C" void kernel_launch(void* const* d_in, const int* in_sizes, int n_in,
                              void* d_out, int out_size, void* d_ws, size_t ws_size,
                              hipStream_t stream)
{
    (void)in_sizes; (void)n_in; (void)out_size; (void)ws_size;
    const float* x     = (const float*)d_in[0];
    const float* Wqkv  = (const float*)d_in[4];
    const float* bqkv  = (const float*)d_in[5];
    const float* Wlin  = (const float*)d_in[6];
    const float* blin  = (const float*)d_in[7];
    const float* Wa    = (const float*)d_in[8];
    const float* Wb    = (const float*)d_in[9];
    const float* temb0 = (const float*)d_in[13];
    const float* temb1 = (const float*)d_in[14];
    const float* semb  = (const float*)d_in[15];
    const float* Wo    = (const float*)d_in[16];
    const float* bo    = (const float*)d_in[17];
    float* out = (float*)d_out;

    // ---- workspace (float offsets), ~60 MB ----
    float* ws   = (float*)d_ws;
    float* CUR  = ws;                                  // 1,536,000
    float* ADJ  = CUR + (long)MAXBW * Mc * Cc;         // 360,000
    float* CAND = ADJ + (long)Mc * Mc;                 // 512,000
    uint*  OB   = (uint*)(CAND + (long)MAXBW * Nc * Cc); // 3,072,000 u32
    float* QHf  = (float*)(OB + (long)MAXBW * Mc * ATTc);
    const long QSZ = (long)MAXBW * Mc * ATTc / 2;      // in floats
    float* QLf  = QHf + QSZ;
    float* KHf  = QLf + QSZ;
    float* KLf  = KHf + QSZ;
    float* VTHf = KLf + QSZ;
    float* VTLf = VTHf + (long)MAXBW * ATTc * MPAD / 2;
    ushort* NAH = (ushort*)(VTLf + (long)MAXBW * ATTc * MPAD / 2);
    ushort* NAL = NAH + Mc * Cc;
    ushort* NBH = NAL + Mc * Cc;
    ushort* NBL = NBH + Mc * Cc;
    ushort* WTH = NBL + Mc * Cc;                       // 64*128 each
    ushort* WTL = WTH + 64 * 128;
    ushort* WQH = WTL + 64 * 128;                      // 384*64 each
    ushort* WQL = WQH + 384 * 64;

    ushort* QH  = (ushort*)QHf;
    ushort* QL  = (ushort*)QLf;
    ushort* KH  = (ushort*)KHf;
    ushort* KL  = (ushort*)KLf;
    ushort* VTH = (ushort*)VTHf;
    ushort* VTL = (ushort*)VTLf;

    const float inv_sqrt_att = 0.08838834764831845f;   // 1/sqrt(128)

    // weight preps (constant across iterations)
    wlin_prep_k<<<dim3(32), dim3(256), 0, stream>>>(Wlin, WTH, WTL);
    wqkv_prep_k<<<dim3(96), dim3(256), 0, stream>>>(Wqkv, WQH, WQL);

    for (int layer = 0; layer < 2; layer++) {
        int Tin = layer ? 10 : 12;
        int nw  = Tin - 2;
        int BW  = Bc * nw;                             // 40 then 32
        int Mtot = BW * Mc;
        const float* src  = layer ? CAND : x;
        const float* temb = layer ? temb1 : temb0;

        long etotal = (long)BW * Mc * Cc;
        embed_window_k<<<dim3((unsigned)((etotal + 255) / 256)), dim3(256), 0, stream>>>(
            src, temb, semb, CUR, Tin, nw, etotal);

        for (int it = 0; it < 3; it++) {
            // adjacency: mean -> NA/NB (bf16 split) -> sigmoid MFMA
            mean_nab_k<<<dim3(38), dim3(256), 0, stream>>>(
                CUR, Wa, Wb, NAH, NAL, NBH, NBL, BW);
            adjmm_k<<<dim3(5, 5), dim3(256), 0, stream>>>(
                NAH, NAL, NBH, NBL, ADJ);

            // QKV projection (R17: B direct, halved CP, 36 KB LDS)
            qkv_mfma_k<<<dim3(BW * 15), dim3(256), 0, stream>>>(
                CUR, WQH, WQL, bqkv, QH, QL, KH, KL, VTH, VTL);

            // fused attention (R14-proven config)
            attn_k<<<dim3(BW * 10), dim3(256), 0, stream>>>(
                QH, QL, KH, KL, VTH, VTL, ADJ, OB, inv_sqrt_att);

            // cur = O @ Wlin + blin, with fused middle-window running max
            wlin_k<<<dim3((Mtot + 127) / 128), dim3(256), 0, stream>>>(
                OB, WTH, WTL, blin, CUR, Mtot, CAND, it == 0 ? 1 : 0);
        }
    }
    output_k<<<dim3(Bc * Nc), dim3(128), 0, stream>>>(CAND, Wo, bo, out);
}

// Round 5
// 775.490 us; speedup vs baseline: 1.8702x; 1.0290x over previous
//
#include <hip/hip_runtime.h>
#include <hip/hip_bf16.h>
#include <math.h>

constexpr int Bc   = 4;
constexpr int Nc   = 200;
constexpr int Cc   = 64;
constexpr int Mc   = 600;    // 3*N
constexpr int ATTc = 128;
constexpr int OUTFc = 128;
constexpr int PREDc = 12;
constexpr int MAXBW = 40;
constexpr int MPAD  = 640;   // padded V^T leading dim

typedef short short4v __attribute__((ext_vector_type(4)));
typedef short short8 __attribute__((ext_vector_type(8)));
typedef float f32x4  __attribute__((ext_vector_type(4)));

static __device__ __forceinline__ void bsplit(float v, short& h, short& l) {
    __hip_bfloat16 hb = __float2bfloat16(v);
    float hf = __bfloat162float(hb);
    __hip_bfloat16 lb = __float2bfloat16(v - hf);
    h = *(short*)&hb; l = *(short*)&lb;
}

// ---------------- embed + sliding window ----------------
__global__ __launch_bounds__(256)
void embed_window_k(const float* __restrict__ src, const float* __restrict__ temb,
                    const float* __restrict__ semb, float* __restrict__ dst,
                    int Tin, int nw, long total)
{
    long idx = (long)blockIdx.x * 256 + threadIdx.x;
    if (idx >= total) return;
    int c = (int)(idx & 63);
    long r = idx >> 6;
    int n = (int)(r % Nc); r /= Nc;
    int j = (int)(r % 3);  r /= 3;
    int w = (int)(r % nw);
    int b = (int)(r / nw);
    int t = w + j;
    dst[idx] = src[(((long)b * Tin + t) * Nc + n) * Cc + c]
             + temb[t * Cc + c] + semb[n * Cc + c];
}

// ------- fused node-mean + NA/NB projection -> bf16 hi/lo outputs ---------
__global__ __launch_bounds__(256)
void mean_nab_k(const float* __restrict__ cur, const float* __restrict__ Wa,
                const float* __restrict__ Wb,
                ushort* __restrict__ NAH, ushort* __restrict__ NAL,
                ushort* __restrict__ NBH, ushort* __restrict__ NBL, int BW)
{
    __shared__ float Ns[64][17];   // [k][row]
    __shared__ float Ws[64][132];  // [k][ Wa | Wb ]
    const int m0 = blockIdx.x * 16;
    const int t = threadIdx.x;
    for (int e = t; e < 1024; e += 256) {
        int r = e >> 4, c4 = (e & 15) << 2;
        *(float4*)&Ws[r][c4]      = *(const float4*)&Wa[r * 64 + c4];
        *(float4*)&Ws[r][64 + c4] = *(const float4*)&Wb[r * 64 + c4];
    }
    {
        int row = t >> 4, c4 = (t & 15) << 2;
        int gm = m0 + row;
        float4 sv = make_float4(0.f, 0.f, 0.f, 0.f);
        if (gm < Mc) {
            for (int bw = 0; bw < BW; bw++) {
                const float4 v = *(const float4*)&cur[((long)bw * Mc + gm) * Cc + c4];
                sv.x += v.x; sv.y += v.y; sv.z += v.z; sv.w += v.w;
            }
        }
        const float inv = 1.f / BW;
        Ns[c4 + 0][row] = sv.x * inv; Ns[c4 + 1][row] = sv.y * inv;
        Ns[c4 + 2][row] = sv.z * inv; Ns[c4 + 3][row] = sv.w * inv;
    }
    __syncthreads();
    const int row = t >> 4, c8 = (t & 15) * 8;
    float acc[8] = {};
    for (int k = 0; k < 64; k++) {
        float a = Ns[k][row];
        float b[8];
        *(float4*)&b[0] = *(const float4*)&Ws[k][c8];
        *(float4*)&b[4] = *(const float4*)&Ws[k][c8 + 4];
#pragma unroll
        for (int j = 0; j < 8; j++) acc[j] += a * b[j];
    }
    int gm = m0 + row;
    if (gm < Mc) {
#pragma unroll
        for (int j = 0; j < 8; j++) {
            int col = c8 + j;
            short h, l;
            bsplit(acc[j], h, l);
            if (col < 64) { NAH[gm * 64 + col] = (ushort)h; NAL[gm * 64 + col] = (ushort)l; }
            else { NBH[gm * 64 + col - 64] = (ushort)h; NBL[gm * 64 + col - 64] = (ushort)l; }
        }
    }
}

// ---- adj = sigmoid( (NA NB^T) / 8 ): split-bf16 MFMA, 128-tiles, grid 5x5 -
__global__ __launch_bounds__(256)
void adjmm_k(const ushort* __restrict__ Ah, const ushort* __restrict__ Al,
             const ushort* __restrict__ Bh, const ushort* __restrict__ Bl,
             float* __restrict__ ADJ)
{
    __shared__ __align__(16) ushort As[2][128][40];
    __shared__ __align__(16) ushort Bs[2][128][40];
    const int m0 = blockIdx.y * 128, n0 = blockIdx.x * 128;
    const int t = threadIdx.x;
    const int lane = t & 63, w = t >> 6;
    const int wm = (w >> 1) * 64, wn = (w & 1) * 64;
    const int lm = lane & 15, lq = lane >> 4;

    f32x4 acc[4][4];
#pragma unroll
    for (int i = 0; i < 4; i++)
#pragma unroll
        for (int j = 0; j < 4; j++)
#pragma unroll
            for (int r = 0; r < 4; r++) acc[i][j][r] = 0.f;

    for (int k0 = 0; k0 < 64; k0 += 32) {
        __syncthreads();
#pragma unroll
        for (int p = 0; p < 2; p++) {
            int e = t + p * 256;
            int row = e >> 2, ks = (e & 3) << 3;
            {
                int gm = m0 + row;
                short8 vh, vl;
#pragma unroll
                for (int q = 0; q < 8; q++) { vh[q] = 0; vl[q] = 0; }
                if (gm < Mc) {
                    vh = *(const short8*)(Ah + (long)gm * 64 + k0 + ks);
                    vl = *(const short8*)(Al + (long)gm * 64 + k0 + ks);
                }
                *(short8*)&As[0][row][ks] = vh;
                *(short8*)&As[1][row][ks] = vl;
            }
            {
                int gn = n0 + row;
                short8 vh, vl;
#pragma unroll
                for (int q = 0; q < 8; q++) { vh[q] = 0; vl[q] = 0; }
                if (gn < Mc) {
                    vh = *(const short8*)(Bh + (long)gn * 64 + k0 + ks);
                    vl = *(const short8*)(Bl + (long)gn * 64 + k0 + ks);
                }
                *(short8*)&Bs[0][row][ks] = vh;
                *(short8*)&Bs[1][row][ks] = vl;
            }
        }
        __syncthreads();

        short8 af[4][2], bf[4][2];
#pragma unroll
        for (int i = 0; i < 4; i++) {
            af[i][0] = *(const short8*)&As[0][wm + i * 16 + lm][lq * 8];
            af[i][1] = *(const short8*)&As[1][wm + i * 16 + lm][lq * 8];
        }
#pragma unroll
        for (int j = 0; j < 4; j++) {
            bf[j][0] = *(const short8*)&Bs[0][wn + j * 16 + lm][lq * 8];
            bf[j][1] = *(const short8*)&Bs[1][wn + j * 16 + lm][lq * 8];
        }
#pragma unroll
        for (int i = 0; i < 4; i++)
#pragma unroll
            for (int j = 0; j < 4; j++) {
                acc[i][j] = __builtin_amdgcn_mfma_f32_16x16x32_bf16(af[i][0], bf[j][0], acc[i][j], 0, 0, 0);
                acc[i][j] = __builtin_amdgcn_mfma_f32_16x16x32_bf16(af[i][0], bf[j][1], acc[i][j], 0, 0, 0);
                acc[i][j] = __builtin_amdgcn_mfma_f32_16x16x32_bf16(af[i][1], bf[j][0], acc[i][j], 0, 0, 0);
            }
    }
#pragma unroll
    for (int i = 0; i < 4; i++) {
        int gmb = m0 + wm + i * 16 + lq * 4;
#pragma unroll
        for (int j = 0; j < 4; j++) {
            int gn = n0 + wn + j * 16 + lm;
            if (gn >= Mc) continue;
#pragma unroll
            for (int r = 0; r < 4; r++) {
                int gm = gmb + r;
                if (gm < Mc)
                    ADJ[(long)gm * Mc + gn] = 1.f / (1.f + __expf(-acc[i][j][r] * 0.125f));
            }
        }
    }
}

// ---------------- Wqkv^T prep: transpose + bf16 hi/lo split ----------------
// WQH/WQL [384][64]: row = output column of Wqkv, col = input channel.
__global__ __launch_bounds__(256)
void wqkv_prep_k(const float* __restrict__ Wqkv,
                 ushort* __restrict__ WQH, ushort* __restrict__ WQL)
{
    int i = blockIdx.x * 256 + threadIdx.x;
    if (i >= 384 * 64) return;
    int n = i >> 6, c = i & 63;
    short h, l;
    bsplit(Wqkv[c * 384 + n], h, l);
    WQH[n * 64 + c] = (ushort)h;
    WQL[n * 64 + c] = (ushort)l;
}

// ---- QKV projection: split-bf16 MFMA, K=64, XCD-swizzled (R14-proven) -----
// A = CUR tile (fp32 -> hi/lo in staging), B = WqkvT hi/lo staged in LDS.
// C routed through packed-uint LDS scratch so all global stores are short8.
__global__ __launch_bounds__(256)
void qkv_mfma_k(const float* __restrict__ CURp,
                const ushort* __restrict__ WQH, const ushort* __restrict__ WQL,
                const float* __restrict__ bias,
                ushort* __restrict__ QH, ushort* __restrict__ QL,
                ushort* __restrict__ KH, ushort* __restrict__ KL,
                ushort* __restrict__ VTH, ushort* __restrict__ VTL)
{
    __shared__ __align__(16) ushort SM[36864];   // 72 KB, multi-purpose
    ushort* AsH = SM;                 // [128][72]
    ushort* AsL = SM + 9216;
    ushort* BsH = SM + 18432;
    ushort* BsL = SM + 27648;
    const int bid = blockIdx.x;
    const int xcd = bid & 7, slot = bid >> 3;
    const int z = (slot / 15) * 8 + xcd;
    const int r15 = slot % 15;
    const int which = r15 % 3;             // 0=q 1=k 2=v
    const int m0 = (r15 / 3) * 128;
    const int nb = which * 128;
    const float* A = CURp + (long)z * Mc * Cc;
    const int t = threadIdx.x;
    const int lane = t & 63, w = t >> 6;
    const int wm = (w >> 1) * 64, wn = (w & 1) * 64;
    const int lm = lane & 15, lq = lane >> 4;

    // ---- stage A: CUR tile 128 rows x 64 k, fp32 -> hi/lo ----
#pragma unroll
    for (int p = 0; p < 8; p++) {
        int e = t + p * 256;              // 0..2047
        int row = e >> 4, k4 = (e & 15) * 4;
        int gm = m0 + row;
        float4 v = make_float4(0.f, 0.f, 0.f, 0.f);
        if (gm < Mc) v = *(const float4*)(A + (long)gm * 64 + k4);
        short4v h4, l4;
        short hs, ls;
        bsplit(v.x, hs, ls); h4[0] = hs; l4[0] = ls;
        bsplit(v.y, hs, ls); h4[1] = hs; l4[1] = ls;
        bsplit(v.z, hs, ls); h4[2] = hs; l4[2] = ls;
        bsplit(v.w, hs, ls); h4[3] = hs; l4[3] = ls;
        *(short4v*)(AsH + row * 72 + k4) = h4;
        *(short4v*)(AsL + row * 72 + k4) = l4;
    }
    // ---- stage B: WqkvT rows nb..nb+127 x 64 ----
#pragma unroll
    for (int p = 0; p < 4; p++) {
        int e = t + p * 256;              // 0..1023
        int row = e >> 3, seg = (e & 7) * 8;
        *(short8*)(BsH + row * 72 + seg) = *(const short8*)(WQH + (long)(nb + row) * 64 + seg);
        *(short8*)(BsL + row * 72 + seg) = *(const short8*)(WQL + (long)(nb + row) * 64 + seg);
    }
    __syncthreads();

    f32x4 acc[4][4];
#pragma unroll
    for (int i = 0; i < 4; i++)
#pragma unroll
        for (int j = 0; j < 4; j++)
#pragma unroll
            for (int r = 0; r < 4; r++) acc[i][j][r] = 0.f;

#pragma unroll
    for (int ks = 0; ks < 2; ks++) {
        short8 af[4][2], bf[4][2];
#pragma unroll
        for (int i = 0; i < 4; i++) {
            af[i][0] = *(const short8*)(AsH + (wm + i * 16 + lm) * 72 + ks * 32 + lq * 8);
            af[i][1] = *(const short8*)(AsL + (wm + i * 16 + lm) * 72 + ks * 32 + lq * 8);
        }
#pragma unroll
        for (int j = 0; j < 4; j++) {
            bf[j][0] = *(const short8*)(BsH + (wn + j * 16 + lm) * 72 + ks * 32 + lq * 8);
            bf[j][1] = *(const short8*)(BsL + (wn + j * 16 + lm) * 72 + ks * 32 + lq * 8);
        }
#pragma unroll
        for (int i = 0; i < 4; i++)
#pragma unroll
            for (int j = 0; j < 4; j++) {
                acc[i][j] = __builtin_amdgcn_mfma_f32_16x16x32_bf16(af[i][0], bf[j][0], acc[i][j], 0, 0, 0);
                acc[i][j] = __builtin_amdgcn_mfma_f32_16x16x32_bf16(af[i][0], bf[j][1], acc[i][j], 0, 0, 0);
                acc[i][j] = __builtin_amdgcn_mfma_f32_16x16x32_bf16(af[i][1], bf[j][0], acc[i][j], 0, 0, 0);
            }
    }
    __syncthreads();   // frags consumed; SM reused as C scratch

    // ---- C -> packed (hi|lo) uint LDS scratch, stride 132 ----
    uint* CP = (uint*)SM;                 // [128][132] uints = 67.6 KB
#pragma unroll
    for (int i = 0; i < 4; i++)
#pragma unroll
        for (int j = 0; j < 4; j++) {
            int col = wn + j * 16 + lm;
            float b = bias[nb + col];
#pragma unroll
            for (int r = 0; r < 4; r++) {
                int row = wm + i * 16 + lq * 4 + r;
                float v = acc[i][j][r] + b;
                if (which == 2) v = fmaxf(v, 0.f);
                short hs, ls;
                bsplit(v, hs, ls);
                CP[row * 132 + col] = ((uint)(ushort)ls << 16) | (uint)(ushort)hs;
            }
        }
    __syncthreads();

    if (which == 2) {
        // V: transposed packed store [col][MPAD] + row
        ushort* vh = VTH + (long)z * ATTc * MPAD;
        ushort* vl = VTL + (long)z * ATTc * MPAD;
#pragma unroll
        for (int p = 0; p < 8; p++) {
            int e = t + p * 256;          // 0..2047
            int col = e >> 4, rg = (e & 15) * 8;
            if (m0 + rg < Mc) {           // 600 % 8 == 0: whole group valid
                short8 h8, l8;
#pragma unroll
                for (int q = 0; q < 8; q++) {
                    uint u = CP[(rg + q) * 132 + col];
                    h8[q] = (short)(u & 0xffff);
                    l8[q] = (short)(u >> 16);
                }
                *(short8*)(vh + (long)col * MPAD + m0 + rg) = h8;
                *(short8*)(vl + (long)col * MPAD + m0 + rg) = l8;
            }
        }
    } else {
        // Q/K: row-major packed store [row][128]
        ushort* dh = (which == 0 ? QH : KH) + (long)z * Mc * ATTc;
        ushort* dl = (which == 0 ? QL : KL) + (long)z * Mc * ATTc;
#pragma unroll
        for (int p = 0; p < 8; p++) {
            int e = t + p * 256;
            int row = e >> 4, seg = (e & 15) * 8;
            int gm = m0 + row;
            if (gm < Mc) {
                short8 h8, l8;
#pragma unroll
                for (int q = 0; q < 8; q++) {
                    uint u = CP[row * 132 + seg + q];
                    h8[q] = (short)(u & 0xffff);
                    l8[q] = (short)(u >> 16);
                }
                *(short8*)(dh + (long)gm * ATTc + seg) = h8;
                *(short8*)(dl + (long)gm * ATTc + seg) = l8;
            }
        }
    }
}

// ---- fused attention (R14-proven): S=QK^T -> P=exp(s)*adj -> PV -----------
// Grid BW*10 XCD-swizzled, 64 q-rows/block, 4 waves x 16 rows, K/V LDS-staged,
// P wave-private. Software-pipelined staging (T14 async split): each round
// writes prefetched regs -> LDS, issues the NEXT round's loads, then MFMAs.
#define ISSUE_K(Dh, Dl, kc_, g_)                                        \
  _Pragma("unroll")                                                     \
  for (int p = 0; p < 4; p++) {                                         \
    int key = (kc_) + srow0 + 32 * p;                                   \
    short8 vh, vl;                                                      \
    _Pragma("unroll")                                                   \
    for (int q2 = 0; q2 < 8; q2++) { vh[q2] = 0; vl[q2] = 0; }          \
    if (key < Mc) {                                                     \
      vh = *(const short8*)(Khz + (long)key * ATTc + (g_) * 64 + sks);  \
      vl = *(const short8*)(Klz + (long)key * ATTc + (g_) * 64 + sks);  \
    }                                                                   \
    Dh[p] = vh; Dl[p] = vl;                                             \
  }

#define ISSUE_V(Dh, Dl, kc_, g_)                                                   \
  _Pragma("unroll")                                                                \
  for (int p = 0; p < 4; p++) {                                                    \
    int att = srow0 + 32 * p;                                                      \
    Dh[p] = *(const short8*)(Vhz + (long)att * MPAD + (kc_) + (g_) * 64 + sks);    \
    Dl[p] = *(const short8*)(Vlz + (long)att * MPAD + (kc_) + (g_) * 64 + sks);    \
  }

#define WRITE_SB(Dh, Dl)                                                \
  _Pragma("unroll")                                                     \
  for (int p = 0; p < 4; p++) {                                         \
    *(short8*)&SB[0][srow0 + 32 * p][sks] = Dh[p];                      \
    *(short8*)&SB[1][srow0 + 32 * p][sks] = Dl[p];                      \
  }

#define MFMA_QK(base_)                                                   \
  _Pragma("unroll")                                                      \
  for (int kk = 0; kk < 2; kk++) {                                       \
    _Pragma("unroll")                                                    \
    for (int j = 0; j < 8; j++) {                                        \
      short8 bh = *(const short8*)&SB[0][j * 16 + lm][kk * 32 + lq * 8]; \
      short8 bl = *(const short8*)&SB[1][j * 16 + lm][kk * 32 + lq * 8]; \
      sacc[j] = __builtin_amdgcn_mfma_f32_16x16x32_bf16(qh[(base_) + kk], bh, sacc[j], 0, 0, 0); \
      sacc[j] = __builtin_amdgcn_mfma_f32_16x16x32_bf16(qh[(base_) + kk], bl, sacc[j], 0, 0, 0); \
      sacc[j] = __builtin_amdgcn_mfma_f32_16x16x32_bf16(ql[(base_) + kk], bh, sacc[j], 0, 0, 0); \
    }                                                                    \
  }

#define MFMA_PV(g_)                                                      \
  _Pragma("unroll")                                                      \
  for (int kk = 0; kk < 2; kk++) {                                       \
    int po = ((g_) * 64 + kk * 32 + lq * 8) ^ ((lm >> 2) << 3);          \
    short8 ph = *(const short8*)&PH[w][lm][po];                          \
    short8 pl = *(const short8*)&PL[w][lm][po];                          \
    _Pragma("unroll")                                                    \
    for (int j = 0; j < 8; j++) {                                        \
      short8 vh = *(const short8*)&SB[0][j * 16 + lm][kk * 32 + lq * 8]; \
      short8 vl = *(const short8*)&SB[1][j * 16 + lm][kk * 32 + lq * 8]; \
      oacc[j] = __builtin_amdgcn_mfma_f32_16x16x32_bf16(ph, vh, oacc[j], 0, 0, 0); \
      oacc[j] = __builtin_amdgcn_mfma_f32_16x16x32_bf16(ph, vl, oacc[j], 0, 0, 0); \
      oacc[j] = __builtin_amdgcn_mfma_f32_16x16x32_bf16(pl, vh, oacc[j], 0, 0, 0); \
    }                                                                    \
  }

__global__ __launch_bounds__(256, 2)
void attn_k(const ushort* __restrict__ QH, const ushort* __restrict__ QL,
            const ushort* __restrict__ KH, const ushort* __restrict__ KL,
            const ushort* __restrict__ VTH, const ushort* __restrict__ VTL,
            const float* __restrict__ adj, uint* __restrict__ OB, float scale)
{
    __shared__ __align__(16) ushort SB[2][128][72];   // K or V stage (64 k)
    __shared__ __align__(16) ushort PH[4][16][152];   // wave-private P hi
    __shared__ __align__(16) ushort PL[4][16][152];   //                lo
    const int bid = blockIdx.x;
    const int xcd = bid & 7, slot = bid >> 3;
    const int z = (slot / 10) * 8 + xcd;
    const int m0 = (slot % 10) * 64;
    const int t = threadIdx.x;
    const int lane = t & 63, w = t >> 6;
    const int lm = lane & 15, lq = lane >> 4;
    const int qrow0 = m0 + w * 16;
    const int srow0 = t >> 3;          // staging row base 0..31
    const int sks   = (t & 7) << 3;    // staging col 0..56 (x8 shorts)

    const ushort* Qhz = QH + (long)z * Mc * ATTc;
    const ushort* Qlz = QL + (long)z * Mc * ATTc;
    const ushort* Khz = KH + (long)z * Mc * ATTc;
    const ushort* Klz = KL + (long)z * Mc * ATTc;
    const ushort* Vhz = VTH + (long)z * ATTc * MPAD;
    const ushort* Vlz = VTL + (long)z * ATTc * MPAD;

    // ---- prefetch round 0 (chunk 0, K half0) ----
    short8 RAh[4], RAl[4], RBh[4], RBl[4];
    ISSUE_K(RAh, RAl, 0, 0);

    // ---- Q fragments ----
    short8 qh[4], ql[4];
    {
        int qr = qrow0 + lm;
        if (qr < Mc) {
            const ushort* qp = Qhz + (long)qr * ATTc;
            const ushort* qp2 = Qlz + (long)qr * ATTc;
#pragma unroll
            for (int ks = 0; ks < 4; ks++) {
                qh[ks] = *(const short8*)(qp + ks * 32 + lq * 8);
                ql[ks] = *(const short8*)(qp2 + ks * 32 + lq * 8);
            }
        } else {
#pragma unroll
            for (int ks = 0; ks < 4; ks++)
#pragma unroll
                for (int q = 0; q < 8; q++) { qh[ks][q] = 0; ql[ks][q] = 0; }
        }
    }

    f32x4 oacc[8];
#pragma unroll
    for (int j = 0; j < 8; j++)
#pragma unroll
        for (int r = 0; r < 4; r++) oacc[j][r] = 0.f;
    float Er[4] = {}, Sr[4] = {};
    float adjv[8][4];

    for (int c = 0; c < 5; c++) {
        const int kc = c * 128;
        f32x4 sacc[8];
#pragma unroll
        for (int j = 0; j < 8; j++)
#pragma unroll
            for (int r = 0; r < 4; r++) sacc[j][r] = 0.f;

        // ---------- round 0: K half0 ----------
        __syncthreads();
        WRITE_SB(RAh, RAl);
        ISSUE_K(RBh, RBl, kc, 1);
        // prefetch this chunk's adj block into regs (consumed 2 phases later)
#pragma unroll
        for (int j = 0; j < 8; j++) {
            int col = kc + j * 16 + lm;
#pragma unroll
            for (int r = 0; r < 4; r++) {
                int row = qrow0 + lq * 4 + r;
                adjv[j][r] = (col < Mc && row < Mc) ? adj[(long)row * Mc + col] : 0.f;
            }
        }
        __syncthreads();
        MFMA_QK(0);

        // ---------- round 1: K half1 ----------
        __syncthreads();
        WRITE_SB(RBh, RBl);
        ISSUE_V(RAh, RAl, kc, 0);
        __syncthreads();
        MFMA_QK(2);

        // ---------- epilogue: P = exp(s*scale)*adj -> wave-private LDS ----
#pragma unroll
        for (int j = 0; j < 8; j++) {
            int col = kc + j * 16 + lm;
            bool cok = col < Mc;
#pragma unroll
            for (int r = 0; r < 4; r++) {
                float e = cok ? __expf(sacc[j][r] * scale) : 0.f;
                float p = e * adjv[j][r];
                Er[r] += e; Sr[r] += p;
                short hs, ls;
                bsplit(p, hs, ls);
                int cs = (j * 16 + lm) ^ (lq << 3);   // row>>2 == lq swizzle
                PH[w][lq * 4 + r][cs] = (ushort)hs;
                PL[w][lq * 4 + r][cs] = (ushort)ls;
            }
        }

        // ---------- round 2: V half0 ----------
        __syncthreads();
        WRITE_SB(RAh, RAl);
        ISSUE_V(RBh, RBl, kc, 1);
        __syncthreads();
        MFMA_PV(0);

        // ---------- round 3: V half1 ----------
        __syncthreads();
        WRITE_SB(RBh, RBl);
        if (c < 4) { ISSUE_K(RAh, RAl, kc + 128, 0); }
        __syncthreads();
        MFMA_PV(1);
    }

    // ---- row sums, then packed bf16 hi/lo store ----
#pragma unroll
    for (int mk = 1; mk <= 8; mk <<= 1)
#pragma unroll
        for (int r = 0; r < 4; r++) {
            Er[r] += __shfl_xor(Er[r], mk, 64);
            Sr[r] += __shfl_xor(Sr[r], mk, 64);
        }
    float inv[4];
#pragma unroll
    for (int r = 0; r < 4; r++) inv[r] = 1.f / (Sr[r] + 1e-8f * Er[r]);
    uint* Oz = OB + (long)z * Mc * ATTc;
#pragma unroll
    for (int j = 0; j < 8; j++)
#pragma unroll
        for (int r = 0; r < 4; r++) {
            int row = qrow0 + lq * 4 + r;
            if (row < Mc) {
                float v = oacc[j][r] * inv[r];
                short hs, ls;
                bsplit(v, hs, ls);
                Oz[(long)row * ATTc + j * 16 + lm] =
                    ((uint)(ushort)ls << 16) | (uint)(ushort)hs;
            }
        }
}

#undef ISSUE_K
#undef ISSUE_V
#undef WRITE_SB
#undef MFMA_QK
#undef MFMA_PV

// ---------------- Wlin^T prep: transpose + bf16 hi/lo split ----------------
__global__ __launch_bounds__(256)
void wlin_prep_k(const float* __restrict__ Wlin,
                 ushort* __restrict__ WTH, ushort* __restrict__ WTL)
{
    int i = blockIdx.x * 256 + threadIdx.x;
    if (i >= 64 * 128) return;
    int c = i >> 7, a = i & 127;
    short h, l;
    bsplit(Wlin[a * 64 + c], h, l);
    WTH[c * 128 + a] = (ushort)h;
    WTL[c * 128 + a] = (ushort)l;
}

// ---- Wlin GEMM: CUR = unpack(OB) @ Wlin + blin; fused cand-max epilogue ---
__global__ __launch_bounds__(256)
void wlin_k(const uint* __restrict__ OB, const ushort* __restrict__ WTH,
            const ushort* __restrict__ WTL, const float* __restrict__ blin,
            float* __restrict__ CUR, int Mtot,
            float* __restrict__ cand, int first)
{
    __shared__ __align__(16) ushort As[2][128][40];
    __shared__ __align__(16) ushort Bs[2][64][136];
    const int m0 = blockIdx.x * 128;
    const int t = threadIdx.x;
    const int lane = t & 63, w = t >> 6;
    const int wm = (w >> 1) * 64, wn = (w & 1) * 32;
    const int lm = lane & 15, lq = lane >> 4;

#pragma unroll
    for (int p = 0; p < 4; p++) {
        int e = t + p * 256;
        int row = e >> 4, seg = (e & 15) << 3;
        *(short8*)&Bs[0][row][seg] = *(const short8*)(WTH + row * 128 + seg);
        *(short8*)&Bs[1][row][seg] = *(const short8*)(WTL + row * 128 + seg);
    }

    f32x4 acc[4][2];
#pragma unroll
    for (int i = 0; i < 4; i++)
#pragma unroll
        for (int j = 0; j < 2; j++)
#pragma unroll
            for (int r = 0; r < 4; r++) acc[i][j][r] = 0.f;

    for (int k0 = 0; k0 < 128; k0 += 32) {
        __syncthreads();
#pragma unroll
        for (int p = 0; p < 2; p++) {
            int e = t + p * 256;
            int row = e >> 2, seg = (e & 3) << 3;
            int gm = m0 + row;
            short8 vh, vl;
#pragma unroll
            for (int q = 0; q < 8; q++) { vh[q] = 0; vl[q] = 0; }
            if (gm < Mtot) {
                const uint4 u0 = *(const uint4*)(OB + (long)gm * 128 + k0 + seg);
                const uint4 u1 = *(const uint4*)(OB + (long)gm * 128 + k0 + seg + 4);
#pragma unroll
                for (int q = 0; q < 4; q++) {
                    uint u = ((const uint*)&u0)[q];
                    vh[q] = (short)(u & 0xffff); vl[q] = (short)(u >> 16);
                }
#pragma unroll
                for (int q = 0; q < 4; q++) {
                    uint u = ((const uint*)&u1)[q];
                    vh[4 + q] = (short)(u & 0xffff); vl[4 + q] = (short)(u >> 16);
                }
            }
            *(short8*)&As[0][row][seg] = vh;
            *(short8*)&As[1][row][seg] = vl;
        }
        __syncthreads();

        short8 af[4][2], bf[2][2];
#pragma unroll
        for (int i = 0; i < 4; i++) {
            af[i][0] = *(const short8*)&As[0][wm + i * 16 + lm][lq * 8];
            af[i][1] = *(const short8*)&As[1][wm + i * 16 + lm][lq * 8];
        }
#pragma unroll
        for (int j = 0; j < 2; j++) {
            bf[j][0] = *(const short8*)&Bs[0][wn + j * 16 + lm][k0 + lq * 8];
            bf[j][1] = *(const short8*)&Bs[1][wn + j * 16 + lm][k0 + lq * 8];
        }
#pragma unroll
        for (int i = 0; i < 4; i++)
#pragma unroll
            for (int j = 0; j < 2; j++) {
                acc[i][j] = __builtin_amdgcn_mfma_f32_16x16x32_bf16(af[i][0], bf[j][0], acc[i][j], 0, 0, 0);
                acc[i][j] = __builtin_amdgcn_mfma_f32_16x16x32_bf16(af[i][0], bf[j][1], acc[i][j], 0, 0, 0);
                acc[i][j] = __builtin_amdgcn_mfma_f32_16x16x32_bf16(af[i][1], bf[j][0], acc[i][j], 0, 0, 0);
            }
    }
#pragma unroll
    for (int i = 0; i < 4; i++) {
        int gmb = m0 + wm + i * 16 + lq * 4;
#pragma unroll
        for (int j = 0; j < 2; j++) {
            int col = wn + j * 16 + lm;
            float b = blin[col];
#pragma unroll
            for (int r = 0; r < 4; r++) {
                int gm = gmb + r;
                if (gm < Mtot) {
                    float v = acc[i][j][r] + b;
                    CUR[(long)gm * 64 + col] = v;
                    int bw = gm / Mc;
                    int m = gm - bw * Mc;
                    if (m >= 2 * Nc) {        // middle-window slice [2N:3N)
                        long o = ((long)bw * Nc + (m - 2 * Nc)) * Cc + col;
                        cand[o] = first ? v : fmaxf(cand[o], v);
                    }
                }
            }
        }
    }
}

// ---------------- output layer ----------------
__global__ __launch_bounds__(128)
void output_k(const float* __restrict__ h2, const float* __restrict__ Wo,
              const float* __restrict__ bo, float* __restrict__ out)
{
    __shared__ float ds[512];
    int row = blockIdx.x;
    int b = row / Nc, n = row % Nc;
    int t = threadIdx.x;
    for (int e = t; e < 512; e += 128) {
        int tt = e >> 6, c = e & 63;
        ds[e] = h2[(((long)b * 8 + tt) * Nc + n) * Cc + c];
    }
    __syncthreads();
    float acc = bo[t];
    for (int e = 0; e < 512; e++) acc += ds[e] * Wo[e * OUTFc + t];
    acc = fmaxf(acc, 0.f);
    for (int p = 0; p < PREDc; p++)
        out[(((long)b * PREDc + p) * Nc + n) * (long)OUTFc + t] = acc;
}

extern "C" void kernel_launch(void* const* d_in, const int* in_sizes, int n_in,
                              void* d_out, int out_size, void* d_ws, size_t ws_size,
                              hipStream_t stream)
{
    (void)in_sizes; (void)n_in; (void)out_size; (void)ws_size;
    const float* x     = (const float*)d_in[0];
    const float* Wqkv  = (const float*)d_in[4];
    const float* bqkv  = (const float*)d_in[5];
    const float* Wlin  = (const float*)d_in[6];
    const float* blin  = (const float*)d_in[7];
    const float* Wa    = (const float*)d_in[8];
    const float* Wb    = (const float*)d_in[9];
    const float* temb0 = (const float*)d_in[13];
    const float* temb1 = (const float*)d_in[14];
    const float* semb  = (const float*)d_in[15];
    const float* Wo    = (const float*)d_in[16];
    const float* bo    = (const float*)d_in[17];
    float* out = (float*)d_out;

    // ---- workspace (float offsets), ~60 MB ----
    float* ws   = (float*)d_ws;
    float* CUR  = ws;                                  // 1,536,000
    float* ADJ  = CUR + (long)MAXBW * Mc * Cc;         // 360,000
    float* CAND = ADJ + (long)Mc * Mc;                 // 512,000
    uint*  OB   = (uint*)(CAND + (long)MAXBW * Nc * Cc); // 3,072,000 u32
    float* QHf  = (float*)(OB + (long)MAXBW * Mc * ATTc);
    const long QSZ = (long)MAXBW * Mc * ATTc / 2;      // in floats
    float* QLf  = QHf + QSZ;
    float* KHf  = QLf + QSZ;
    float* KLf  = KHf + QSZ;
    float* VTHf = KLf + QSZ;
    float* VTLf = VTHf + (long)MAXBW * ATTc * MPAD / 2;
    ushort* NAH = (ushort*)(VTLf + (long)MAXBW * ATTc * MPAD / 2);
    ushort* NAL = NAH + Mc * Cc;
    ushort* NBH = NAL + Mc * Cc;
    ushort* NBL = NBH + Mc * Cc;
    ushort* WTH = NBL + Mc * Cc;                       // 64*128 each
    ushort* WTL = WTH + 64 * 128;
    ushort* WQH = WTL + 64 * 128;                      // 384*64 each
    ushort* WQL = WQH + 384 * 64;

    ushort* QH  = (ushort*)QHf;
    ushort* QL  = (ushort*)QLf;
    ushort* KH  = (ushort*)KHf;
    ushort* KL  = (ushort*)KLf;
    ushort* VTH = (ushort*)VTHf;
    ushort* VTL = (ushort*)VTLf;

    const float inv_sqrt_att = 0.08838834764831845f;   // 1/sqrt(128)

    // weight preps (constant across iterations)
    wlin_prep_k<<<dim3(32), dim3(256), 0, stream>>>(Wlin, WTH, WTL);
    wqkv_prep_k<<<dim3(96), dim3(256), 0, stream>>>(Wqkv, WQH, WQL);

    for (int layer = 0; layer < 2; layer++) {
        int Tin = layer ? 10 : 12;
        int nw  = Tin - 2;
        int BW  = Bc * nw;                             // 40 then 32
        int Mtot = BW * Mc;
        const float* src  = layer ? CAND : x;
        const float* temb = layer ? temb1 : temb0;

        long etotal = (long)BW * Mc * Cc;
        embed_window_k<<<dim3((unsigned)((etotal + 255) / 256)), dim3(256), 0, stream>>>(
            src, temb, semb, CUR, Tin, nw, etotal);

        for (int it = 0; it < 3; it++) {
            // adjacency: mean -> NA/NB (bf16 split) -> sigmoid MFMA
            mean_nab_k<<<dim3(38), dim3(256), 0, stream>>>(
                CUR, Wa, Wb, NAH, NAL, NBH, NBL, BW);
            adjmm_k<<<dim3(5, 5), dim3(256), 0, stream>>>(
                NAH, NAL, NBH, NBL, ADJ);

            // QKV projection (R14-proven config)
            qkv_mfma_k<<<dim3(BW * 15), dim3(256), 0, stream>>>(
                CUR, WQH, WQL, bqkv, QH, QL, KH, KL, VTH, VTL);

            // fused attention (R14-proven config)
            attn_k<<<dim3(BW * 10), dim3(256), 0, stream>>>(
                QH, QL, KH, KL, VTH, VTL, ADJ, OB, inv_sqrt_att);

            // cur = O @ Wlin + blin, with fused middle-window running max
            wlin_k<<<dim3((Mtot + 127) / 128), dim3(256), 0, stream>>>(
                OB, WTH, WTL, blin, CUR, Mtot, CAND, it == 0 ? 1 : 0);
        }
    }
    output_k<<<dim3(Bc * Nc), dim3(128), 0, stream>>>(CAND, Wo, bo, out);
}

// Round 6
// 722.889 us; speedup vs baseline: 2.0062x; 1.0728x over previous
//
#include <hip/hip_runtime.h>
#include <hip/hip_bf16.h>
#include <math.h>

constexpr int Bc   = 4;
constexpr int Nc   = 200;
constexpr int Cc   = 64;
constexpr int Mc   = 600;    // 3*N
constexpr int ATTc = 128;
constexpr int OUTFc = 128;
constexpr int PREDc = 12;
constexpr int MAXBW = 40;
constexpr int MPAD  = 640;   // padded V^T leading dim

typedef short short4v __attribute__((ext_vector_type(4)));
typedef short short8 __attribute__((ext_vector_type(8)));
typedef float f32x4  __attribute__((ext_vector_type(4)));

static __device__ __forceinline__ void bsplit(float v, short& h, short& l) {
    __hip_bfloat16 hb = __float2bfloat16(v);
    float hf = __bfloat162float(hb);
    __hip_bfloat16 lb = __float2bfloat16(v - hf);
    h = *(short*)&hb; l = *(short*)&lb;
}

// ---------------- embed + sliding window ----------------
__global__ __launch_bounds__(256)
void embed_window_k(const float* __restrict__ src, const float* __restrict__ temb,
                    const float* __restrict__ semb, float* __restrict__ dst,
                    int Tin, int nw, long total)
{
    long idx = (long)blockIdx.x * 256 + threadIdx.x;
    if (idx >= total) return;
    int c = (int)(idx & 63);
    long r = idx >> 6;
    int n = (int)(r % Nc); r /= Nc;
    int j = (int)(r % 3);  r /= 3;
    int w = (int)(r % nw);
    int b = (int)(r / nw);
    int t = w + j;
    dst[idx] = src[(((long)b * Tin + t) * Nc + n) * Cc + c]
             + temb[t * Cc + c] + semb[n * Cc + c];
}

// ------- fused node-mean + NA/NB projection -> bf16 hi/lo outputs ---------
__global__ __launch_bounds__(256)
void mean_nab_k(const float* __restrict__ cur, const float* __restrict__ Wa,
                const float* __restrict__ Wb,
                ushort* __restrict__ NAH, ushort* __restrict__ NAL,
                ushort* __restrict__ NBH, ushort* __restrict__ NBL, int BW)
{
    __shared__ float Ns[64][17];   // [k][row]
    __shared__ float Ws[64][132];  // [k][ Wa | Wb ]
    const int m0 = blockIdx.x * 16;
    const int t = threadIdx.x;
    for (int e = t; e < 1024; e += 256) {
        int r = e >> 4, c4 = (e & 15) << 2;
        *(float4*)&Ws[r][c4]      = *(const float4*)&Wa[r * 64 + c4];
        *(float4*)&Ws[r][64 + c4] = *(const float4*)&Wb[r * 64 + c4];
    }
    {
        int row = t >> 4, c4 = (t & 15) << 2;
        int gm = m0 + row;
        float4 sv = make_float4(0.f, 0.f, 0.f, 0.f);
        if (gm < Mc) {
            for (int bw = 0; bw < BW; bw++) {
                const float4 v = *(const float4*)&cur[((long)bw * Mc + gm) * Cc + c4];
                sv.x += v.x; sv.y += v.y; sv.z += v.z; sv.w += v.w;
            }
        }
        const float inv = 1.f / BW;
        Ns[c4 + 0][row] = sv.x * inv; Ns[c4 + 1][row] = sv.y * inv;
        Ns[c4 + 2][row] = sv.z * inv; Ns[c4 + 3][row] = sv.w * inv;
    }
    __syncthreads();
    const int row = t >> 4, c8 = (t & 15) * 8;
    float acc[8] = {};
    for (int k = 0; k < 64; k++) {
        float a = Ns[k][row];
        float b[8];
        *(float4*)&b[0] = *(const float4*)&Ws[k][c8];
        *(float4*)&b[4] = *(const float4*)&Ws[k][c8 + 4];
#pragma unroll
        for (int j = 0; j < 8; j++) acc[j] += a * b[j];
    }
    int gm = m0 + row;
    if (gm < Mc) {
#pragma unroll
        for (int j = 0; j < 8; j++) {
            int col = c8 + j;
            short h, l;
            bsplit(acc[j], h, l);
            if (col < 64) { NAH[gm * 64 + col] = (ushort)h; NAL[gm * 64 + col] = (ushort)l; }
            else { NBH[gm * 64 + col - 64] = (ushort)h; NBL[gm * 64 + col - 64] = (ushort)l; }
        }
    }
}

// ---------------- combined one-shot weight prep ----------------------------
// blocks 0..31: Wlin^T split (64*128); blocks 32..127: Wqkv^T split (384*64)
__global__ __launch_bounds__(256)
void prep_k(const float* __restrict__ Wlin,
            ushort* __restrict__ WTH, ushort* __restrict__ WTL,
            const float* __restrict__ Wqkv,
            ushort* __restrict__ WQH, ushort* __restrict__ WQL)
{
    int i = blockIdx.x * 256 + threadIdx.x;
    if (i < 64 * 128) {
        int c = i >> 7, a = i & 127;
        short h, l;
        bsplit(Wlin[a * 64 + c], h, l);
        WTH[c * 128 + a] = (ushort)h;
        WTL[c * 128 + a] = (ushort)l;
    } else {
        int j = i - 64 * 128;
        if (j < 384 * 64) {
            int n = j >> 6, c = j & 63;
            short h, l;
            bsplit(Wqkv[c * 384 + n], h, l);
            WQH[n * 64 + c] = (ushort)h;
            WQL[n * 64 + c] = (ushort)l;
        }
    }
}

// ---- merged QKV projection + adjacency MM ---------------------------------
// Blocks [0, nqkv): R14-proven qkv_mfma body (XCD-swizzled, 72 KB SM).
// Blocks [nqkv, nqkv+25): adjmm body (As/Bs aliased into SM, 40 KB).
// Both are independent (need only mean_nab outputs / CUR); attn consumes both.
__global__ __launch_bounds__(256)
void qkv_adj_k(const float* __restrict__ CURp,
               const ushort* __restrict__ WQH, const ushort* __restrict__ WQL,
               const float* __restrict__ bias,
               ushort* __restrict__ QH, ushort* __restrict__ QL,
               ushort* __restrict__ KH, ushort* __restrict__ KL,
               ushort* __restrict__ VTH, ushort* __restrict__ VTL,
               const ushort* __restrict__ Ah, const ushort* __restrict__ Al,
               const ushort* __restrict__ Bh, const ushort* __restrict__ Bl,
               float* __restrict__ ADJ, int nqkv)
{
    __shared__ __align__(16) ushort SM[36864];   // 72 KB, multi-purpose
    const int t = threadIdx.x;
    const int lane = t & 63, w = t >> 6;
    const int lm = lane & 15, lq = lane >> 4;

    if ((int)blockIdx.x >= nqkv) {
        // ================= adjmm body =================
        const int b2 = blockIdx.x - nqkv;
        const int m0 = (b2 / 5) * 128, n0 = (b2 % 5) * 128;
        ushort (*As)[128][40] = (ushort (*)[128][40])(SM);          // 20 KB
        ushort (*Bs)[128][40] = (ushort (*)[128][40])(SM + 10240);  // 20 KB
        const int wm = (w >> 1) * 64, wn = (w & 1) * 64;

        f32x4 acc[4][4];
#pragma unroll
        for (int i = 0; i < 4; i++)
#pragma unroll
            for (int j = 0; j < 4; j++)
#pragma unroll
                for (int r = 0; r < 4; r++) acc[i][j][r] = 0.f;

        for (int k0 = 0; k0 < 64; k0 += 32) {
            __syncthreads();
#pragma unroll
            for (int p = 0; p < 2; p++) {
                int e = t + p * 256;
                int row = e >> 2, ks = (e & 3) << 3;
                {
                    int gm = m0 + row;
                    short8 vh, vl;
#pragma unroll
                    for (int q = 0; q < 8; q++) { vh[q] = 0; vl[q] = 0; }
                    if (gm < Mc) {
                        vh = *(const short8*)(Ah + (long)gm * 64 + k0 + ks);
                        vl = *(const short8*)(Al + (long)gm * 64 + k0 + ks);
                    }
                    *(short8*)&As[0][row][ks] = vh;
                    *(short8*)&As[1][row][ks] = vl;
                }
                {
                    int gn = n0 + row;
                    short8 vh, vl;
#pragma unroll
                    for (int q = 0; q < 8; q++) { vh[q] = 0; vl[q] = 0; }
                    if (gn < Mc) {
                        vh = *(const short8*)(Bh + (long)gn * 64 + k0 + ks);
                        vl = *(const short8*)(Bl + (long)gn * 64 + k0 + ks);
                    }
                    *(short8*)&Bs[0][row][ks] = vh;
                    *(short8*)&Bs[1][row][ks] = vl;
                }
            }
            __syncthreads();

            short8 af[4][2], bf[4][2];
#pragma unroll
            for (int i = 0; i < 4; i++) {
                af[i][0] = *(const short8*)&As[0][wm + i * 16 + lm][lq * 8];
                af[i][1] = *(const short8*)&As[1][wm + i * 16 + lm][lq * 8];
            }
#pragma unroll
            for (int j = 0; j < 4; j++) {
                bf[j][0] = *(const short8*)&Bs[0][wn + j * 16 + lm][lq * 8];
                bf[j][1] = *(const short8*)&Bs[1][wn + j * 16 + lm][lq * 8];
            }
#pragma unroll
            for (int i = 0; i < 4; i++)
#pragma unroll
                for (int j = 0; j < 4; j++) {
                    acc[i][j] = __builtin_amdgcn_mfma_f32_16x16x32_bf16(af[i][0], bf[j][0], acc[i][j], 0, 0, 0);
                    acc[i][j] = __builtin_amdgcn_mfma_f32_16x16x32_bf16(af[i][0], bf[j][1], acc[i][j], 0, 0, 0);
                    acc[i][j] = __builtin_amdgcn_mfma_f32_16x16x32_bf16(af[i][1], bf[j][0], acc[i][j], 0, 0, 0);
                }
        }
#pragma unroll
        for (int i = 0; i < 4; i++) {
            int gmb = m0 + wm + i * 16 + lq * 4;
#pragma unroll
            for (int j = 0; j < 4; j++) {
                int gn = n0 + wn + j * 16 + lm;
                if (gn >= Mc) continue;
#pragma unroll
                for (int r = 0; r < 4; r++) {
                    int gm = gmb + r;
                    if (gm < Mc)
                        ADJ[(long)gm * Mc + gn] = 1.f / (1.f + __expf(-acc[i][j][r] * 0.125f));
                }
            }
        }
        return;
    }

    // ================= qkv body (R14-proven) =================
    ushort* AsH = SM;                 // [128][72]
    ushort* AsL = SM + 9216;
    ushort* BsH = SM + 18432;
    ushort* BsL = SM + 27648;
    const int bid = blockIdx.x;
    const int xcd = bid & 7, slot = bid >> 3;
    const int z = (slot / 15) * 8 + xcd;
    const int r15 = slot % 15;
    const int which = r15 % 3;             // 0=q 1=k 2=v
    const int m0 = (r15 / 3) * 128;
    const int nb = which * 128;
    const float* A = CURp + (long)z * Mc * Cc;
    const int wm = (w >> 1) * 64, wn = (w & 1) * 64;

    // ---- stage A: CUR tile 128 rows x 64 k, fp32 -> hi/lo ----
#pragma unroll
    for (int p = 0; p < 8; p++) {
        int e = t + p * 256;              // 0..2047
        int row = e >> 4, k4 = (e & 15) * 4;
        int gm = m0 + row;
        float4 v = make_float4(0.f, 0.f, 0.f, 0.f);
        if (gm < Mc) v = *(const float4*)(A + (long)gm * 64 + k4);
        short4v h4, l4;
        short hs, ls;
        bsplit(v.x, hs, ls); h4[0] = hs; l4[0] = ls;
        bsplit(v.y, hs, ls); h4[1] = hs; l4[1] = ls;
        bsplit(v.z, hs, ls); h4[2] = hs; l4[2] = ls;
        bsplit(v.w, hs, ls); h4[3] = hs; l4[3] = ls;
        *(short4v*)(AsH + row * 72 + k4) = h4;
        *(short4v*)(AsL + row * 72 + k4) = l4;
    }
    // ---- stage B: WqkvT rows nb..nb+127 x 64 ----
#pragma unroll
    for (int p = 0; p < 4; p++) {
        int e = t + p * 256;              // 0..1023
        int row = e >> 3, seg = (e & 7) * 8;
        *(short8*)(BsH + row * 72 + seg) = *(const short8*)(WQH + (long)(nb + row) * 64 + seg);
        *(short8*)(BsL + row * 72 + seg) = *(const short8*)(WQL + (long)(nb + row) * 64 + seg);
    }
    __syncthreads();

    f32x4 acc[4][4];
#pragma unroll
    for (int i = 0; i < 4; i++)
#pragma unroll
        for (int j = 0; j < 4; j++)
#pragma unroll
            for (int r = 0; r < 4; r++) acc[i][j][r] = 0.f;

#pragma unroll
    for (int ks = 0; ks < 2; ks++) {
        short8 af[4][2], bf[4][2];
#pragma unroll
        for (int i = 0; i < 4; i++) {
            af[i][0] = *(const short8*)(AsH + (wm + i * 16 + lm) * 72 + ks * 32 + lq * 8);
            af[i][1] = *(const short8*)(AsL + (wm + i * 16 + lm) * 72 + ks * 32 + lq * 8);
        }
#pragma unroll
        for (int j = 0; j < 4; j++) {
            bf[j][0] = *(const short8*)(BsH + (wn + j * 16 + lm) * 72 + ks * 32 + lq * 8);
            bf[j][1] = *(const short8*)(BsL + (wn + j * 16 + lm) * 72 + ks * 32 + lq * 8);
        }
#pragma unroll
        for (int i = 0; i < 4; i++)
#pragma unroll
            for (int j = 0; j < 4; j++) {
                acc[i][j] = __builtin_amdgcn_mfma_f32_16x16x32_bf16(af[i][0], bf[j][0], acc[i][j], 0, 0, 0);
                acc[i][j] = __builtin_amdgcn_mfma_f32_16x16x32_bf16(af[i][0], bf[j][1], acc[i][j], 0, 0, 0);
                acc[i][j] = __builtin_amdgcn_mfma_f32_16x16x32_bf16(af[i][1], bf[j][0], acc[i][j], 0, 0, 0);
            }
    }
    __syncthreads();   // frags consumed; SM reused as C scratch

    // ---- C -> packed (hi|lo) uint LDS scratch, stride 132 ----
    uint* CP = (uint*)SM;                 // [128][132] uints = 67.6 KB
#pragma unroll
    for (int i = 0; i < 4; i++)
#pragma unroll
        for (int j = 0; j < 4; j++) {
            int col = wn + j * 16 + lm;
            float b = bias[nb + col];
#pragma unroll
            for (int r = 0; r < 4; r++) {
                int row = wm + i * 16 + lq * 4 + r;
                float v = acc[i][j][r] + b;
                if (which == 2) v = fmaxf(v, 0.f);
                short hs, ls;
                bsplit(v, hs, ls);
                CP[row * 132 + col] = ((uint)(ushort)ls << 16) | (uint)(ushort)hs;
            }
        }
    __syncthreads();

    if (which == 2) {
        // V: transposed packed store [col][MPAD] + row
        ushort* vh = VTH + (long)z * ATTc * MPAD;
        ushort* vl = VTL + (long)z * ATTc * MPAD;
#pragma unroll
        for (int p = 0; p < 8; p++) {
            int e = t + p * 256;          // 0..2047
            int col = e >> 4, rg = (e & 15) * 8;
            if (m0 + rg < Mc) {           // 600 % 8 == 0: whole group valid
                short8 h8, l8;
#pragma unroll
                for (int q = 0; q < 8; q++) {
                    uint u = CP[(rg + q) * 132 + col];
                    h8[q] = (short)(u & 0xffff);
                    l8[q] = (short)(u >> 16);
                }
                *(short8*)(vh + (long)col * MPAD + m0 + rg) = h8;
                *(short8*)(vl + (long)col * MPAD + m0 + rg) = l8;
            }
        }
    } else {
        // Q/K: row-major packed store [row][128]
        ushort* dh = (which == 0 ? QH : KH) + (long)z * Mc * ATTc;
        ushort* dl = (which == 0 ? QL : KL) + (long)z * Mc * ATTc;
#pragma unroll
        for (int p = 0; p < 8; p++) {
            int e = t + p * 256;
            int row = e >> 4, seg = (e & 15) * 8;
            int gm = m0 + row;
            if (gm < Mc) {
                short8 h8, l8;
#pragma unroll
                for (int q = 0; q < 8; q++) {
                    uint u = CP[row * 132 + seg + q];
                    h8[q] = (short)(u & 0xffff);
                    l8[q] = (short)(u >> 16);
                }
                *(short8*)(dh + (long)gm * ATTc + seg) = h8;
                *(short8*)(dl + (long)gm * ATTc + seg) = l8;
            }
        }
    }
}

// ---- fused attention (R14-proven): S=QK^T -> P=exp(s)*adj -> PV -----------
// Grid BW*10 XCD-swizzled, 64 q-rows/block, 4 waves x 16 rows, K/V LDS-staged,
// P wave-private. Software-pipelined staging (T14 async split): each round
// writes prefetched regs -> LDS, issues the NEXT round's loads, then MFMAs.
#define ISSUE_K(Dh, Dl, kc_, g_)                                        \
  _Pragma("unroll")                                                     \
  for (int p = 0; p < 4; p++) {                                         \
    int key = (kc_) + srow0 + 32 * p;                                   \
    short8 vh, vl;                                                      \
    _Pragma("unroll")                                                   \
    for (int q2 = 0; q2 < 8; q2++) { vh[q2] = 0; vl[q2] = 0; }          \
    if (key < Mc) {                                                     \
      vh = *(const short8*)(Khz + (long)key * ATTc + (g_) * 64 + sks);  \
      vl = *(const short8*)(Klz + (long)key * ATTc + (g_) * 64 + sks);  \
    }                                                                   \
    Dh[p] = vh; Dl[p] = vl;                                             \
  }

#define ISSUE_V(Dh, Dl, kc_, g_)                                                   \
  _Pragma("unroll")                                                                \
  for (int p = 0; p < 4; p++) {                                                    \
    int att = srow0 + 32 * p;                                                      \
    Dh[p] = *(const short8*)(Vhz + (long)att * MPAD + (kc_) + (g_) * 64 + sks);    \
    Dl[p] = *(const short8*)(Vlz + (long)att * MPAD + (kc_) + (g_) * 64 + sks);    \
  }

#define WRITE_SB(Dh, Dl)                                                \
  _Pragma("unroll")                                                     \
  for (int p = 0; p < 4; p++) {                                         \
    *(short8*)&SB[0][srow0 + 32 * p][sks] = Dh[p];                      \
    *(short8*)&SB[1][srow0 + 32 * p][sks] = Dl[p];                      \
  }

#define MFMA_QK(base_)                                                   \
  _Pragma("unroll")                                                      \
  for (int kk = 0; kk < 2; kk++) {                                       \
    _Pragma("unroll")                                                    \
    for (int j = 0; j < 8; j++) {                                        \
      short8 bh = *(const short8*)&SB[0][j * 16 + lm][kk * 32 + lq * 8]; \
      short8 bl = *(const short8*)&SB[1][j * 16 + lm][kk * 32 + lq * 8]; \
      sacc[j] = __builtin_amdgcn_mfma_f32_16x16x32_bf16(qh[(base_) + kk], bh, sacc[j], 0, 0, 0); \
      sacc[j] = __builtin_amdgcn_mfma_f32_16x16x32_bf16(qh[(base_) + kk], bl, sacc[j], 0, 0, 0); \
      sacc[j] = __builtin_amdgcn_mfma_f32_16x16x32_bf16(ql[(base_) + kk], bh, sacc[j], 0, 0, 0); \
    }                                                                    \
  }

#define MFMA_PV(g_)                                                      \
  _Pragma("unroll")                                                      \
  for (int kk = 0; kk < 2; kk++) {                                       \
    int po = ((g_) * 64 + kk * 32 + lq * 8) ^ ((lm >> 2) << 3);          \
    short8 ph = *(const short8*)&PH[w][lm][po];                          \
    short8 pl = *(const short8*)&PL[w][lm][po];                          \
    _Pragma("unroll")                                                    \
    for (int j = 0; j < 8; j++) {                                        \
      short8 vh = *(const short8*)&SB[0][j * 16 + lm][kk * 32 + lq * 8]; \
      short8 vl = *(const short8*)&SB[1][j * 16 + lm][kk * 32 + lq * 8]; \
      oacc[j] = __builtin_amdgcn_mfma_f32_16x16x32_bf16(ph, vh, oacc[j], 0, 0, 0); \
      oacc[j] = __builtin_amdgcn_mfma_f32_16x16x32_bf16(ph, vl, oacc[j], 0, 0, 0); \
      oacc[j] = __builtin_amdgcn_mfma_f32_16x16x32_bf16(pl, vh, oacc[j], 0, 0, 0); \
    }                                                                    \
  }

__global__ __launch_bounds__(256, 2)
void attn_k(const ushort* __restrict__ QH, const ushort* __restrict__ QL,
            const ushort* __restrict__ KH, const ushort* __restrict__ KL,
            const ushort* __restrict__ VTH, const ushort* __restrict__ VTL,
            const float* __restrict__ adj, uint* __restrict__ OB, float scale)
{
    __shared__ __align__(16) ushort SB[2][128][72];   // K or V stage (64 k)
    __shared__ __align__(16) ushort PH[4][16][152];   // wave-private P hi
    __shared__ __align__(16) ushort PL[4][16][152];   //                lo
    const int bid = blockIdx.x;
    const int xcd = bid & 7, slot = bid >> 3;
    const int z = (slot / 10) * 8 + xcd;
    const int m0 = (slot % 10) * 64;
    const int t = threadIdx.x;
    const int lane = t & 63, w = t >> 6;
    const int lm = lane & 15, lq = lane >> 4;
    const int qrow0 = m0 + w * 16;
    const int srow0 = t >> 3;          // staging row base 0..31
    const int sks   = (t & 7) << 3;    // staging col 0..56 (x8 shorts)

    const ushort* Qhz = QH + (long)z * Mc * ATTc;
    const ushort* Qlz = QL + (long)z * Mc * ATTc;
    const ushort* Khz = KH + (long)z * Mc * ATTc;
    const ushort* Klz = KL + (long)z * Mc * ATTc;
    const ushort* Vhz = VTH + (long)z * ATTc * MPAD;
    const ushort* Vlz = VTL + (long)z * ATTc * MPAD;

    // ---- prefetch round 0 (chunk 0, K half0) ----
    short8 RAh[4], RAl[4], RBh[4], RBl[4];
    ISSUE_K(RAh, RAl, 0, 0);

    // ---- Q fragments ----
    short8 qh[4], ql[4];
    {
        int qr = qrow0 + lm;
        if (qr < Mc) {
            const ushort* qp = Qhz + (long)qr * ATTc;
            const ushort* qp2 = Qlz + (long)qr * ATTc;
#pragma unroll
            for (int ks = 0; ks < 4; ks++) {
                qh[ks] = *(const short8*)(qp + ks * 32 + lq * 8);
                ql[ks] = *(const short8*)(qp2 + ks * 32 + lq * 8);
            }
        } else {
#pragma unroll
            for (int ks = 0; ks < 4; ks++)
#pragma unroll
                for (int q = 0; q < 8; q++) { qh[ks][q] = 0; ql[ks][q] = 0; }
        }
    }

    f32x4 oacc[8];
#pragma unroll
    for (int j = 0; j < 8; j++)
#pragma unroll
        for (int r = 0; r < 4; r++) oacc[j][r] = 0.f;
    float Er[4] = {}, Sr[4] = {};
    float adjv[8][4];

    for (int c = 0; c < 5; c++) {
        const int kc = c * 128;
        f32x4 sacc[8];
#pragma unroll
        for (int j = 0; j < 8; j++)
#pragma unroll
            for (int r = 0; r < 4; r++) sacc[j][r] = 0.f;

        // ---------- round 0: K half0 ----------
        __syncthreads();
        WRITE_SB(RAh, RAl);
        ISSUE_K(RBh, RBl, kc, 1);
        // prefetch this chunk's adj block into regs (consumed 2 phases later)
#pragma unroll
        for (int j = 0; j < 8; j++) {
            int col = kc + j * 16 + lm;
#pragma unroll
            for (int r = 0; r < 4; r++) {
                int row = qrow0 + lq * 4 + r;
                adjv[j][r] = (col < Mc && row < Mc) ? adj[(long)row * Mc + col] : 0.f;
            }
        }
        __syncthreads();
        MFMA_QK(0);

        // ---------- round 1: K half1 ----------
        __syncthreads();
        WRITE_SB(RBh, RBl);
        ISSUE_V(RAh, RAl, kc, 0);
        __syncthreads();
        MFMA_QK(2);

        // ---------- epilogue: P = exp(s*scale)*adj -> wave-private LDS ----
#pragma unroll
        for (int j = 0; j < 8; j++) {
            int col = kc + j * 16 + lm;
            bool cok = col < Mc;
#pragma unroll
            for (int r = 0; r < 4; r++) {
                float e = cok ? __expf(sacc[j][r] * scale) : 0.f;
                float p = e * adjv[j][r];
                Er[r] += e; Sr[r] += p;
                short hs, ls;
                bsplit(p, hs, ls);
                int cs = (j * 16 + lm) ^ (lq << 3);   // row>>2 == lq swizzle
                PH[w][lq * 4 + r][cs] = (ushort)hs;
                PL[w][lq * 4 + r][cs] = (ushort)ls;
            }
        }

        // ---------- round 2: V half0 ----------
        __syncthreads();
        WRITE_SB(RAh, RAl);
        ISSUE_V(RBh, RBl, kc, 1);
        __syncthreads();
        MFMA_PV(0);

        // ---------- round 3: V half1 ----------
        __syncthreads();
        WRITE_SB(RBh, RBl);
        if (c < 4) { ISSUE_K(RAh, RAl, kc + 128, 0); }
        __syncthreads();
        MFMA_PV(1);
    }

    // ---- row sums, then packed bf16 hi/lo store ----
#pragma unroll
    for (int mk = 1; mk <= 8; mk <<= 1)
#pragma unroll
        for (int r = 0; r < 4; r++) {
            Er[r] += __shfl_xor(Er[r], mk, 64);
            Sr[r] += __shfl_xor(Sr[r], mk, 64);
        }
    float inv[4];
#pragma unroll
    for (int r = 0; r < 4; r++) inv[r] = 1.f / (Sr[r] + 1e-8f * Er[r]);
    uint* Oz = OB + (long)z * Mc * ATTc;
#pragma unroll
    for (int j = 0; j < 8; j++)
#pragma unroll
        for (int r = 0; r < 4; r++) {
            int row = qrow0 + lq * 4 + r;
            if (row < Mc) {
                float v = oacc[j][r] * inv[r];
                short hs, ls;
                bsplit(v, hs, ls);
                Oz[(long)row * ATTc + j * 16 + lm] =
                    ((uint)(ushort)ls << 16) | (uint)(ushort)hs;
            }
        }
}

#undef ISSUE_K
#undef ISSUE_V
#undef WRITE_SB
#undef MFMA_QK
#undef MFMA_PV

// ---- Wlin GEMM: CUR = unpack(OB) @ Wlin + blin; fused cand-max epilogue ---
__global__ __launch_bounds__(256)
void wlin_k(const uint* __restrict__ OB, const ushort* __restrict__ WTH,
            const ushort* __restrict__ WTL, const float* __restrict__ blin,
            float* __restrict__ CUR, int Mtot,
            float* __restrict__ cand, int first)
{
    __shared__ __align__(16) ushort As[2][128][40];
    __shared__ __align__(16) ushort Bs[2][64][136];
    const int m0 = blockIdx.x * 128;
    const int t = threadIdx.x;
    const int lane = t & 63, w = t >> 6;
    const int wm = (w >> 1) * 64, wn = (w & 1) * 32;
    const int lm = lane & 15, lq = lane >> 4;

#pragma unroll
    for (int p = 0; p < 4; p++) {
        int e = t + p * 256;
        int row = e >> 4, seg = (e & 15) << 3;
        *(short8*)&Bs[0][row][seg] = *(const short8*)(WTH + row * 128 + seg);
        *(short8*)&Bs[1][row][seg] = *(const short8*)(WTL + row * 128 + seg);
    }

    f32x4 acc[4][2];
#pragma unroll
    for (int i = 0; i < 4; i++)
#pragma unroll
        for (int j = 0; j < 2; j++)
#pragma unroll
            for (int r = 0; r < 4; r++) acc[i][j][r] = 0.f;

    for (int k0 = 0; k0 < 128; k0 += 32) {
        __syncthreads();
#pragma unroll
        for (int p = 0; p < 2; p++) {
            int e = t + p * 256;
            int row = e >> 2, seg = (e & 3) << 3;
            int gm = m0 + row;
            short8 vh, vl;
#pragma unroll
            for (int q = 0; q < 8; q++) { vh[q] = 0; vl[q] = 0; }
            if (gm < Mtot) {
                const uint4 u0 = *(const uint4*)(OB + (long)gm * 128 + k0 + seg);
                const uint4 u1 = *(const uint4*)(OB + (long)gm * 128 + k0 + seg + 4);
#pragma unroll
                for (int q = 0; q < 4; q++) {
                    uint u = ((const uint*)&u0)[q];
                    vh[q] = (short)(u & 0xffff); vl[q] = (short)(u >> 16);
                }
#pragma unroll
                for (int q = 0; q < 4; q++) {
                    uint u = ((const uint*)&u1)[q];
                    vh[4 + q] = (short)(u & 0xffff); vl[4 + q] = (short)(u >> 16);
                }
            }
            *(short8*)&As[0][row][seg] = vh;
            *(short8*)&As[1][row][seg] = vl;
        }
        __syncthreads();

        short8 af[4][2], bf[2][2];
#pragma unroll
        for (int i = 0; i < 4; i++) {
            af[i][0] = *(const short8*)&As[0][wm + i * 16 + lm][lq * 8];
            af[i][1] = *(const short8*)&As[1][wm + i * 16 + lm][lq * 8];
        }
#pragma unroll
        for (int j = 0; j < 2; j++) {
            bf[j][0] = *(const short8*)&Bs[0][wn + j * 16 + lm][k0 + lq * 8];
            bf[j][1] = *(const short8*)&Bs[1][wn + j * 16 + lm][k0 + lq * 8];
        }
#pragma unroll
        for (int i = 0; i < 4; i++)
#pragma unroll
            for (int j = 0; j < 2; j++) {
                acc[i][j] = __builtin_amdgcn_mfma_f32_16x16x32_bf16(af[i][0], bf[j][0], acc[i][j], 0, 0, 0);
                acc[i][j] = __builtin_amdgcn_mfma_f32_16x16x32_bf16(af[i][0], bf[j][1], acc[i][j], 0, 0, 0);
                acc[i][j] = __builtin_amdgcn_mfma_f32_16x16x32_bf16(af[i][1], bf[j][0], acc[i][j], 0, 0, 0);
            }
    }
#pragma unroll
    for (int i = 0; i < 4; i++) {
        int gmb = m0 + wm + i * 16 + lq * 4;
#pragma unroll
        for (int j = 0; j < 2; j++) {
            int col = wn + j * 16 + lm;
            float b = blin[col];
#pragma unroll
            for (int r = 0; r < 4; r++) {
                int gm = gmb + r;
                if (gm < Mtot) {
                    float v = acc[i][j][r] + b;
                    CUR[(long)gm * 64 + col] = v;
                    int bw = gm / Mc;
                    int m = gm - bw * Mc;
                    if (m >= 2 * Nc) {        // middle-window slice [2N:3N)
                        long o = ((long)bw * Nc + (m - 2 * Nc)) * Cc + col;
                        cand[o] = first ? v : fmaxf(cand[o], v);
                    }
                }
            }
        }
    }
}

// ---------------- output layer ----------------
__global__ __launch_bounds__(128)
void output_k(const float* __restrict__ h2, const float* __restrict__ Wo,
              const float* __restrict__ bo, float* __restrict__ out)
{
    __shared__ float ds[512];
    int row = blockIdx.x;
    int b = row / Nc, n = row % Nc;
    int t = threadIdx.x;
    for (int e = t; e < 512; e += 128) {
        int tt = e >> 6, c = e & 63;
        ds[e] = h2[(((long)b * 8 + tt) * Nc + n) * Cc + c];
    }
    __syncthreads();
    float acc = bo[t];
    for (int e = 0; e < 512; e++) acc += ds[e] * Wo[e * OUTFc + t];
    acc = fmaxf(acc, 0.f);
    for (int p = 0; p < PREDc; p++)
        out[(((long)b * PREDc + p) * Nc + n) * (long)OUTFc + t] = acc;
}

extern "C" void kernel_launch(void* const* d_in, const int* in_sizes, int n_in,
                              void* d_out, int out_size, void* d_ws, size_t ws_size,
                              hipStream_t stream)
{
    (void)in_sizes; (void)n_in; (void)out_size; (void)ws_size;
    const float* x     = (const float*)d_in[0];
    const float* Wqkv  = (const float*)d_in[4];
    const float* bqkv  = (const float*)d_in[5];
    const float* Wlin  = (const float*)d_in[6];
    const float* blin  = (const float*)d_in[7];
    const float* Wa    = (const float*)d_in[8];
    const float* Wb    = (const float*)d_in[9];
    const float* temb0 = (const float*)d_in[13];
    const float* temb1 = (const float*)d_in[14];
    const float* semb  = (const float*)d_in[15];
    const float* Wo    = (const float*)d_in[16];
    const float* bo    = (const float*)d_in[17];
    float* out = (float*)d_out;

    // ---- workspace (float offsets), ~60 MB ----
    float* ws   = (float*)d_ws;
    float* CUR  = ws;                                  // 1,536,000
    float* ADJ  = CUR + (long)MAXBW * Mc * Cc;         // 360,000
    float* CAND = ADJ + (long)Mc * Mc;                 // 512,000
    uint*  OB   = (uint*)(CAND + (long)MAXBW * Nc * Cc); // 3,072,000 u32
    float* QHf  = (float*)(OB + (long)MAXBW * Mc * ATTc);
    const long QSZ = (long)MAXBW * Mc * ATTc / 2;      // in floats
    float* QLf  = QHf + QSZ;
    float* KHf  = QLf + QSZ;
    float* KLf  = KHf + QSZ;
    float* VTHf = KLf + QSZ;
    float* VTLf = VTHf + (long)MAXBW * ATTc * MPAD / 2;
    ushort* NAH = (ushort*)(VTLf + (long)MAXBW * ATTc * MPAD / 2);
    ushort* NAL = NAH + Mc * Cc;
    ushort* NBH = NAL + Mc * Cc;
    ushort* NBL = NBH + Mc * Cc;
    ushort* WTH = NBL + Mc * Cc;                       // 64*128 each
    ushort* WTL = WTH + 64 * 128;
    ushort* WQH = WTL + 64 * 128;                      // 384*64 each
    ushort* WQL = WQH + 384 * 64;

    ushort* QH  = (ushort*)QHf;
    ushort* QL  = (ushort*)QLf;
    ushort* KH  = (ushort*)KHf;
    ushort* KL  = (ushort*)KLf;
    ushort* VTH = (ushort*)VTHf;
    ushort* VTL = (ushort*)VTLf;

    const float inv_sqrt_att = 0.08838834764831845f;   // 1/sqrt(128)

    // one-shot weight prep (both transposed bf16 hi/lo splits)
    prep_k<<<dim3(128), dim3(256), 0, stream>>>(Wlin, WTH, WTL, Wqkv, WQH, WQL);

    for (int layer = 0; layer < 2; layer++) {
        int Tin = layer ? 10 : 12;
        int nw  = Tin - 2;
        int BW  = Bc * nw;                             // 40 then 32
        int Mtot = BW * Mc;
        const float* src  = layer ? CAND : x;
        const float* temb = layer ? temb1 : temb0;

        long etotal = (long)BW * Mc * Cc;
        embed_window_k<<<dim3((unsigned)((etotal + 255) / 256)), dim3(256), 0, stream>>>(
            src, temb, semb, CUR, Tin, nw, etotal);

        for (int it = 0; it < 3; it++) {
            // node-mean -> NA/NB (bf16 split)
            mean_nab_k<<<dim3(38), dim3(256), 0, stream>>>(
                CUR, Wa, Wb, NAH, NAL, NBH, NBL, BW);

            // merged: QKV projection (blocks 0..BW*15) + adjacency MM (25 tail blocks)
            int nqkv = BW * 15;
            qkv_adj_k<<<dim3(nqkv + 25), dim3(256), 0, stream>>>(
                CUR, WQH, WQL, bqkv, QH, QL, KH, KL, VTH, VTL,
                NAH, NAL, NBH, NBL, ADJ, nqkv);

            // fused attention (R14-proven config)
            attn_k<<<dim3(BW * 10), dim3(256), 0, stream>>>(
                QH, QL, KH, KL, VTH, VTL, ADJ, OB, inv_sqrt_att);

            // cur = O @ Wlin + blin, with fused middle-window running max
            wlin_k<<<dim3((Mtot + 127) / 128), dim3(256), 0, stream>>>(
                OB, WTH, WTL, blin, CUR, Mtot, CAND, it == 0 ? 1 : 0);
        }
    }
    output_k<<<dim3(Bc * Nc), dim3(128), 0, stream>>>(CAND, Wo, bo, out);
}